// Round 2
// baseline (4322.206 us; speedup 1.0000x reference)
//
#include <hip/hip_runtime.h>
#include <hip/hip_bf16.h>

// EncoderDecoderConvLSTM — Round 13: barrier-free main loop, 4 blocks/CU.
// R12 was 1 block/CU (100 KB LDS) with 9 per-tap barriers: no inter-block
// overlap -> 24 us/round vs ~7 us throughput floor. Now: 256-thr/4-wave/1-row
// blocks, LDS = swizzled B halo only (26 KB), A fragments loaded directly from
// L2-resident W with half-tap register prefetch, ZERO barriers after the
// initial stage. __launch_bounds__(256,4) caps VGPR at 128 -> 16 waves/CU.
// Grid (batch, row) so same-batch adjacent rows share an XCD L2 (halo hits).
// h [b][4096][64] bf16; c f32; W [9][256][64] bf16 plain; fused LSTM epilogue.

#define HW 4096
#define NF 64

typedef __attribute__((ext_vector_type(8))) short bf16x8;
typedef __attribute__((ext_vector_type(4))) float f32x4;

__device__ __forceinline__ float fsig(float v) {
  return __builtin_amdgcn_rcpf(1.f + __expf(-v));
}
__device__ __forceinline__ float ftanh(float v) {
  float vc = fminf(fmaxf(v, -15.f), 15.f);
  float e = __expf(2.f * vc);
  return (e - 1.f) * __builtin_amdgcn_rcpf(e + 1.f);
}
__device__ __forceinline__ float bf2f(short s) {
  union { unsigned u; float f; } a;
  a.u = ((unsigned)(unsigned short)s) << 16;
  return a.f;
}
__device__ __forceinline__ short f2bf(float f) {  // RNE
  union { float f; unsigned u; } a;
  a.f = f;
  unsigned r = (a.u + 0x7fff + ((a.u >> 16) & 1)) >> 16;
  return (short)r;
}

// 4 waves, wave = wnf (16-oc slice per gate). LDS: Bs[3][66][64] halo
// (slot s holds px=s-1; slots 0/65 zero; XOR-swizzle ^(s&7)<<3 on short idx
// -> conflict-free ds_read_b128), xs[3][64] for the encoder x-row.
template <bool HAS_X>
__global__ __launch_bounds__(256, 4) void lstm_mfma_k(
    const short* __restrict__ hin,   // [32][4096][64] bf16
    const short* __restrict__ W,     // [9][256][64] bf16
    const float* __restrict__ wx,    // [256][9] f32 (x-part) or null
    const float* __restrict__ xpl,   // x + t*HW (batch stride 12*HW) or null
    const float* __restrict__ bias,  // [256] f32
    const float* __restrict__ cin,   // [32][4096][64] f32
    short* __restrict__ hout,
    float* __restrict__ cout) {
  const int b = blockIdx.x;        // 0..31 batch (fast dim -> XCD spread)
  const int y = blockIdx.y;        // 0..63 row   (same-b rows co-XCD)
  const int tid = threadIdx.x;
  const int lane = tid & 63;
  const int wnf = tid >> 6;        // 0..3 nf slice
  const int col = lane & 15;
  const int quad = lane >> 4;

  __shared__ short Bs[3 * 66 * 64];
  __shared__ float xs[3][64];

  const short* hb = hin + (size_t)b * (HW * 64);
  // ---- stage B halo: rows y-1..y+1, 3 x 64 px x 64 ch, swizzled ----
#pragma unroll
  for (int i = 0; i < 6; ++i) {
    const int t = tid + i * 256;           // 0..1535
    const int r = t >> 9;                  // 0..2
    const int c = t & 511;
    const int px = c >> 3, ch0 = (c & 7) * 8;
    const int py = y - 1 + r;
    bf16x8 v = {0, 0, 0, 0, 0, 0, 0, 0};
    if (py >= 0 && py < 64)
      v = *reinterpret_cast<const bf16x8*>(hb + ((py * 64 + px) * 64) + ch0);
    *reinterpret_cast<bf16x8*>(
        &Bs[(((r * 66 + px + 1) * 64) + ch0) ^ ((((px + 1) & 7)) << 3)]) = v;
  }
  if (tid < 48) {  // zero x-border slots 0 and 65: 3 rows x 2 x 8 chunks
    const int r = tid >> 4;
    const int s = ((tid >> 3) & 1) * 65;
    const int ch0 = (tid & 7) * 8;
    bf16x8 z = {0, 0, 0, 0, 0, 0, 0, 0};
    *reinterpret_cast<bf16x8*>(
        &Bs[(((r * 66 + s) * 64) + ch0) ^ ((s & 7) << 3)]) = z;
  }
  if (HAS_X) {
    if (tid < 192) {
      const float* xb = xpl + (size_t)b * (12 * HW);
      const int r = tid >> 6, cx = tid & 63;
      const int py = y - 1 + r;
      xs[r][cx] = (py >= 0 && py < 64) ? xb[py * 64 + cx] : 0.f;
    }
  }

  // per-wave W base: row (oc) = g*64 + wnf*16 + col, 16B chunk at quad*8
  const short* Wl = W + ((wnf * 16 + col) * 64 + quad * 8);
  bf16x8 acur[4];
#pragma unroll
  for (int g = 0; g < 4; ++g)   // preload (tap0, kc0) — overlaps staging
    acur[g] = *reinterpret_cast<const bf16x8*>(Wl + g * 4096);

  __syncthreads();   // the ONLY barrier

  f32x4 acc[4][4];  // [gate][n-tile]
#pragma unroll
  for (int g = 0; g < 4; ++g) {
    const int oc0 = g * 64 + wnf * 16 + quad * 4;
#pragma unroll
    for (int nt = 0; nt < 4; ++nt)
#pragma unroll
      for (int r = 0; r < 4; ++r) acc[g][nt][r] = bias[oc0 + r];
  }

  if (HAS_X) {
#pragma unroll
    for (int nt = 0; nt < 4; ++nt) {
      const int px = nt * 16 + col;
#pragma unroll
      for (int tap = 0; tap < 9; ++tap) {
        const int pxx = px + (tap % 3) - 1;
        const float xv = (pxx >= 0 && pxx < 64) ? xs[tap / 3][pxx] : 0.f;
#pragma unroll
        for (int g = 0; g < 4; ++g) {
          const int oc0 = g * 64 + wnf * 16 + quad * 4;
#pragma unroll
          for (int r = 0; r < 4; ++r)
            acc[g][nt][r] = fmaf(xv, wx[(oc0 + r) * 9 + tap], acc[g][nt][r]);
        }
      }
    }
  }

  // ---- main loop: NO barriers. A from L2 (half-tap prefetch), B from LDS.
#pragma unroll
  for (int tap = 0; tap < 9; ++tap) {
    const int hr = tap / 3;
    const int sb = col + tap % 3;       // slot for nt=0 (= px+dx+1)
    const int sx = (sb & 7) << 3;
    const int brow = (hr * 66 + sb) * 64;
#pragma unroll
    for (int kc = 0; kc < 2; ++kc) {
      bf16x8 anx[4];
      if (!(tap == 8 && kc == 1)) {   // issue next half-tap's A loads
        const int ntap = kc ? tap + 1 : tap;
        const int nkc = kc ^ 1;
#pragma unroll
        for (int g = 0; g < 4; ++g)
          anx[g] = *reinterpret_cast<const bf16x8*>(Wl + ntap * 16384 +
                                                    nkc * 32 + g * 4096);
      }
      const int bb = (brow + kc * 32 + quad * 8) ^ sx;
      bf16x8 bfr[4];
#pragma unroll
      for (int nt = 0; nt < 4; ++nt)
        bfr[nt] = *reinterpret_cast<const bf16x8*>(&Bs[bb + nt * 1024]);
      __builtin_amdgcn_s_setprio(1);
#pragma unroll
      for (int g = 0; g < 4; ++g)
#pragma unroll
        for (int nt = 0; nt < 4; ++nt)
          acc[g][nt] = __builtin_amdgcn_mfma_f32_16x16x32_bf16(
              acur[g], bfr[nt], acc[g][nt], 0, 0, 0);
      __builtin_amdgcn_s_setprio(0);
      if (!(tap == 8 && kc == 1)) {
#pragma unroll
        for (int g = 0; g < 4; ++g) acur[g] = anx[g];
      }
    }
  }

  // ---- in-register epilogue ----
  const int nf0 = wnf * 16 + quad * 4;
#pragma unroll
  for (int nt = 0; nt < 4; ++nt) {
    const int px = nt * 16 + col;
    const size_t pix = (size_t)b * HW + y * 64 + px;
    f32x4 cold = *reinterpret_cast<const f32x4*>(cin + pix * 64 + nf0);
    f32x4 cnew;
    short hnew[4];
#pragma unroll
    for (int r = 0; r < 4; ++r) {
      float i_ = fsig(acc[0][nt][r]);
      float f_ = fsig(acc[1][nt][r]);
      float o_ = fsig(acc[2][nt][r]);
      float g_ = ftanh(acc[3][nt][r]);
      float cn = fmaf(f_, cold[r], i_ * g_);
      cnew[r] = cn;
      hnew[r] = f2bf(o_ * ftanh(cn));
    }
    *reinterpret_cast<f32x4*>(cout + pix * 64 + nf0) = cnew;
    short4 hv = make_short4(hnew[0], hnew[1], hnew[2], hnew[3]);
    *reinterpret_cast<short4*>(hout + pix * 64 + nf0) = hv;
  }
}

// head: y[b,t,pix] = b_cnn + sum_{f,tap} wc2[tap][f] * h[pix+tap][f]
__global__ __launch_bounds__(256) void head_k(const short* __restrict__ h,
                                              const float* __restrict__ wc2,
                                              const float* __restrict__ bc,
                                              float* __restrict__ yout, int t) {
  const int tid = blockIdx.x * 256 + threadIdx.x;  // 131072 threads
  const int pix = tid & 4095;
  const int b = tid >> 12;
  const int x0 = pix & 63, y0 = pix >> 6;
  float acc = bc[0];
  const short* hb = h + (size_t)b * (HW * 64);
#pragma unroll
  for (int tap = 0; tap < 9; ++tap) {
    const int yy = y0 + tap / 3 - 1, xx = x0 + (tap % 3) - 1;
    if (yy < 0 || yy > 63 || xx < 0 || xx > 63) continue;
    const short* hp = hb + (yy * 64 + xx) * 64;
    const float* wp = wc2 + tap * 64;
#pragma unroll
    for (int f8 = 0; f8 < 8; ++f8) {
      bf16x8 v = *reinterpret_cast<const bf16x8*>(hp + f8 * 8);
#pragma unroll
      for (int j = 0; j < 8; ++j) acc = fmaf(wp[f8 * 8 + j], bf2f(v[j]), acc);
    }
  }
  yout[(size_t)(b * 12 + t) * HW + pix] = acc;
}

// encoder-vector output: transpose [b][pix][ch] bf16 -> [b][ch][pix] f32
__global__ __launch_bounds__(256) void ev_out_k(const short* __restrict__ h,
                                                float* __restrict__ out) {
  __shared__ float tl[64][65];
  const int b = blockIdx.y, pg = blockIdx.x;
  const int p0 = pg * 64;
  {
    const int pixl = threadIdx.x >> 2, c0 = (threadIdx.x & 3) * 16;
    const short* hp = h + ((size_t)b * HW + p0 + pixl) * 64 + c0;
#pragma unroll
    for (int i = 0; i < 16; ++i) tl[pixl][c0 + i] = bf2f(hp[i]);
  }
  __syncthreads();
  {
    const int ch = threadIdx.x >> 2, q0 = (threadIdx.x & 3) * 16;
    float* op = out + ((size_t)b * 64 + ch) * (size_t)HW + p0 + q0;
#pragma unroll
    for (int i = 0; i < 16; ++i) op[i] = tl[q0 + i][ch];
  }
}

// W_enc [256][65][3][3] f32 -> Wh bf16 [9][256][64] (h part) + wx f32 [256][9]
__global__ __launch_bounds__(256) void reo_enc_k(const float* __restrict__ src,
                                                 short* __restrict__ Wh,
                                                 float* __restrict__ wx) {
  const int idx = blockIdx.x * 256 + threadIdx.x;
  if (idx < 9 * 256 * 64) {
    const int tap = idx >> 14, oc = (idx >> 6) & 255, c = idx & 63;
    Wh[idx] = f2bf(src[(oc * 65 + (c + 1)) * 9 + tap]);
  }
  if (idx < 256 * 9) {
    const int oc = idx / 9, tap = idx % 9;
    wx[idx] = src[(oc * 65 + 0) * 9 + tap];
  }
}

// W_dec [256][128][3][3] f32 -> Wx bf16 [9][256][64], Wsum bf16 (x+h parts)
__global__ __launch_bounds__(256) void reo_dec_k(const float* __restrict__ src,
                                                 short* __restrict__ Wx,
                                                 short* __restrict__ Ws) {
  const int idx = blockIdx.x * 256 + threadIdx.x;
  if (idx >= 9 * 256 * 64) return;
  const int tap = idx >> 14, oc = (idx >> 6) & 255, c = idx & 63;
  const float a = src[(oc * 128 + c) * 9 + tap];
  const float b = src[(oc * 128 + 64 + c) * 9 + tap];
  Wx[idx] = f2bf(a);
  Ws[idx] = f2bf(a + b);
}

// W_cnn [64][9] f32 -> [9][64] f32
__global__ __launch_bounds__(256) void reo_cnn_k(const float* __restrict__ src,
                                                 float* __restrict__ wc2) {
  const int idx = blockIdx.x * 256 + threadIdx.x;
  if (idx >= 576) return;
  wc2[idx] = src[(idx % 64) * 9 + (idx / 64)];
}

extern "C" void kernel_launch(void* const* d_in, const int* in_sizes, int n_in,
                              void* d_out, int out_size, void* d_ws, size_t ws_size,
                              hipStream_t stream) {
  const float* x = (const float*)d_in[0];       // [32,12,1,64,64] f32
  const float* W_enc = (const float*)d_in[2];
  const float* b_enc = (const float*)d_in[3];
  const float* W_dec = (const float*)d_in[4];
  const float* b_dec = (const float*)d_in[5];
  const float* W_cnn = (const float*)d_in[6];
  const float* b_cnn = (const float*)d_in[7];
  float* out = (float*)d_out;
  float* out_y = out;                 // [32][12][4096]
  float* out_ev = out + 1572864;      // [32][64][4096]

  float* ws = (float*)d_ws;
  float* cA = ws;                                // 8388608 f
  float* cB = cA + 8388608;                      // 8388608 f
  short* hA = (short*)(cB + 8388608);            // 8388608 sh
  short* hB = hA + 8388608;                      // 8388608 sh
  short* WEh = hB + 8388608;                     // 147456 sh
  short* WDx = WEh + 147456;                     // 147456 sh
  short* WDs = WDx + 147456;                     // 147456 sh
  float* wx = (float*)(WDs + 147456);            // 2304 f
  float* wc2 = wx + 2304;                        // 576 f  (~101 MB total)

  reo_enc_k<<<(147456 + 255) / 256, 256, 0, stream>>>(W_enc, WEh, wx);
  reo_dec_k<<<(147456 + 255) / 256, 256, 0, stream>>>(W_dec, WDx, WDs);
  reo_cnn_k<<<3, 256, 0, stream>>>(W_cnn, wc2);

  hipMemsetAsync(hA, 0, 8388608 * sizeof(short), stream);
  hipMemsetAsync(cA, 0, 8388608 * sizeof(float), stream);

  dim3 gridL(32, 64), blkL(256);   // x=batch (XCD-fast), y=row; 1 row/block
  dim3 gridE(64, 32), blkE(256);
  short *ha = hA, *hb = hB;
  float *ca = cA, *cb = cB;

  // ---- encoder ----
  for (int t = 0; t < 12; ++t) {
    lstm_mfma_k<true><<<gridL, blkL, 0, stream>>>(ha, WEh, wx, x + t * HW,
                                                  b_enc, ca, hb, cb);
    { short* tm = ha; ha = hb; hb = tm; }
    { float* tm = ca; ca = cb; cb = tm; }
  }
  // ha = h_enc -> output 1 (transposed to [b][ch][pix] f32)
  ev_out_k<<<gridE, blkE, 0, stream>>>(ha, out_ev);

  // fresh zero c for decoder
  hipMemsetAsync(cb, 0, 8388608 * sizeof(float), stream);
  { float* tm = ca; ca = cb; cb = tm; }  // ca = zeroed c

  // ---- decoder ----
  for (int t = 0; t < 12; ++t) {
    lstm_mfma_k<false><<<gridL, blkL, 0, stream>>>(
        ha, (t == 0) ? WDx : WDs, nullptr, nullptr, b_dec, ca, hb, cb);
    { short* tm = ha; ha = hb; hb = tm; }
    { float* tm = ca; ca = cb; cb = tm; }
    head_k<<<512, 256, 0, stream>>>(ha, wc2, b_cnn, out_y, t);
  }
}

// Round 3
// 2808.683 us; speedup vs baseline: 1.5389x; 1.5389x over previous
//
#include <hip/hip_runtime.h>
#include <hip/hip_bf16.h>

// EncoderDecoderConvLSTM — Round 14: barrier-free loop, registers FIXED.
// R13's __launch_bounds__(256,4) capped arch-VGPRs at 64 -> scratch spills
// (WRITE 497 MB, FETCH 243 MB of spill traffic). Same structure, but plain
// __launch_bounds__(256) and no explicit prefetch rotation: fully-unrolled
// tap loop with compile-time W offsets lets the compiler pipeline A-loads
// within its own register budget (~160-200 VGPR -> 2-3 blocks/CU).
// LDS = swizzled B halo only (26 KB). Zero barriers after initial stage.
// Grid (batch, row): same-batch adjacent rows share an XCD L2 (halo hits).
// h [b][4096][64] bf16; c f32; W [9][256][64] bf16 plain; fused LSTM epilogue.

#define HW 4096
#define NF 64

typedef __attribute__((ext_vector_type(8))) short bf16x8;
typedef __attribute__((ext_vector_type(4))) float f32x4;

__device__ __forceinline__ float fsig(float v) {
  return __builtin_amdgcn_rcpf(1.f + __expf(-v));
}
__device__ __forceinline__ float ftanh(float v) {
  float vc = fminf(fmaxf(v, -15.f), 15.f);
  float e = __expf(2.f * vc);
  return (e - 1.f) * __builtin_amdgcn_rcpf(e + 1.f);
}
__device__ __forceinline__ float bf2f(short s) {
  union { unsigned u; float f; } a;
  a.u = ((unsigned)(unsigned short)s) << 16;
  return a.f;
}
__device__ __forceinline__ short f2bf(float f) {  // RNE
  union { float f; unsigned u; } a;
  a.f = f;
  unsigned r = (a.u + 0x7fff + ((a.u >> 16) & 1)) >> 16;
  return (short)r;
}

// 4 waves, wave = wnf (16-oc slice per gate). LDS: Bs[3][66][64] halo
// (slot s holds px=s-1; slots 0/65 zero; XOR-swizzle ^(s&7)<<3 on short idx
// -> conflict-free ds_read_b128), xs[3][64] for the encoder x-row.
template <bool HAS_X>
__global__ __launch_bounds__(256) void lstm_mfma_k(
    const short* __restrict__ hin,   // [32][4096][64] bf16
    const short* __restrict__ W,     // [9][256][64] bf16
    const float* __restrict__ wx,    // [256][9] f32 (x-part) or null
    const float* __restrict__ xpl,   // x + t*HW (batch stride 12*HW) or null
    const float* __restrict__ bias,  // [256] f32
    const float* __restrict__ cin,   // [32][4096][64] f32
    short* __restrict__ hout,
    float* __restrict__ cout) {
  const int b = blockIdx.x;        // 0..31 batch (fast dim -> XCD spread)
  const int y = blockIdx.y;        // 0..63 row   (same-b rows co-XCD)
  const int tid = threadIdx.x;
  const int lane = tid & 63;
  const int wnf = tid >> 6;        // 0..3 nf slice
  const int col = lane & 15;
  const int quad = lane >> 4;

  __shared__ short Bs[3 * 66 * 64];
  __shared__ float xs[3][64];

  const short* hb = hin + (size_t)b * (HW * 64);
  // ---- stage B halo: rows y-1..y+1, 3 x 64 px x 64 ch, swizzled ----
#pragma unroll
  for (int i = 0; i < 6; ++i) {
    const int t = tid + i * 256;           // 0..1535
    const int r = t >> 9;                  // 0..2
    const int c = t & 511;
    const int px = c >> 3, ch0 = (c & 7) * 8;
    const int py = y - 1 + r;
    bf16x8 v = {0, 0, 0, 0, 0, 0, 0, 0};
    if (py >= 0 && py < 64)
      v = *reinterpret_cast<const bf16x8*>(hb + ((py * 64 + px) * 64) + ch0);
    *reinterpret_cast<bf16x8*>(
        &Bs[(((r * 66 + px + 1) * 64) + ch0) ^ ((((px + 1) & 7)) << 3)]) = v;
  }
  if (tid < 48) {  // zero x-border slots 0 and 65: 3 rows x 2 x 8 chunks
    const int r = tid >> 4;
    const int s = ((tid >> 3) & 1) * 65;
    const int ch0 = (tid & 7) * 8;
    bf16x8 z = {0, 0, 0, 0, 0, 0, 0, 0};
    *reinterpret_cast<bf16x8*>(
        &Bs[(((r * 66 + s) * 64) + ch0) ^ ((s & 7) << 3)]) = z;
  }
  if (HAS_X) {
    if (tid < 192) {
      const float* xb = xpl + (size_t)b * (12 * HW);
      const int r = tid >> 6, cx = tid & 63;
      const int py = y - 1 + r;
      xs[r][cx] = (py >= 0 && py < 64) ? xb[py * 64 + cx] : 0.f;
    }
  }
  __syncthreads();   // the ONLY barrier

  f32x4 acc[4][4];  // [gate][n-tile]
#pragma unroll
  for (int g = 0; g < 4; ++g) {
    const int oc0 = g * 64 + wnf * 16 + quad * 4;
#pragma unroll
    for (int nt = 0; nt < 4; ++nt)
#pragma unroll
      for (int r = 0; r < 4; ++r) acc[g][nt][r] = bias[oc0 + r];
  }

  if (HAS_X) {
#pragma unroll
    for (int nt = 0; nt < 4; ++nt) {
      const int px = nt * 16 + col;
#pragma unroll
      for (int tap = 0; tap < 9; ++tap) {
        const int pxx = px + (tap % 3) - 1;
        const float xv = (pxx >= 0 && pxx < 64) ? xs[tap / 3][pxx] : 0.f;
#pragma unroll
        for (int g = 0; g < 4; ++g) {
          const int oc0 = g * 64 + wnf * 16 + quad * 4;
#pragma unroll
          for (int r = 0; r < 4; ++r)
            acc[g][nt][r] = fmaf(xv, wx[(oc0 + r) * 9 + tap], acc[g][nt][r]);
        }
      }
    }
  }

  // per-wave W base: row (oc) = g*64 + wnf*16 + col, 16B chunk at quad*8
  const short* Wl = W + ((wnf * 16 + col) * 64 + quad * 8);

  // ---- main loop: NO barriers. A from L1/L2 (compile-time offsets,
  // compiler pipelines), B from LDS (conflict-free swizzled ds_read_b128).
#pragma unroll
  for (int tap = 0; tap < 9; ++tap) {
    const int hr = tap / 3;
    const int sb = col + tap % 3;       // slot for nt=0 (= px+dx+1)
    const int sx = (sb & 7) << 3;
    const int brow = (hr * 66 + sb) * 64;
#pragma unroll
    for (int kc = 0; kc < 2; ++kc) {
      bf16x8 a[4], bfr[4];
#pragma unroll
      for (int g = 0; g < 4; ++g)
        a[g] = *reinterpret_cast<const bf16x8*>(Wl + tap * 16384 + kc * 32 +
                                                g * 4096);
      const int bb = (brow + kc * 32 + quad * 8) ^ sx;
#pragma unroll
      for (int nt = 0; nt < 4; ++nt)
        bfr[nt] = *reinterpret_cast<const bf16x8*>(&Bs[bb + nt * 1024]);
      __builtin_amdgcn_s_setprio(1);
#pragma unroll
      for (int g = 0; g < 4; ++g)
#pragma unroll
        for (int nt = 0; nt < 4; ++nt)
          acc[g][nt] = __builtin_amdgcn_mfma_f32_16x16x32_bf16(
              a[g], bfr[nt], acc[g][nt], 0, 0, 0);
      __builtin_amdgcn_s_setprio(0);
    }
  }

  // ---- in-register epilogue ----
  const int nf0 = wnf * 16 + quad * 4;
#pragma unroll
  for (int nt = 0; nt < 4; ++nt) {
    const int px = nt * 16 + col;
    const size_t pix = (size_t)b * HW + y * 64 + px;
    f32x4 cold = *reinterpret_cast<const f32x4*>(cin + pix * 64 + nf0);
    f32x4 cnew;
    short hnew[4];
#pragma unroll
    for (int r = 0; r < 4; ++r) {
      float i_ = fsig(acc[0][nt][r]);
      float f_ = fsig(acc[1][nt][r]);
      float o_ = fsig(acc[2][nt][r]);
      float g_ = ftanh(acc[3][nt][r]);
      float cn = fmaf(f_, cold[r], i_ * g_);
      cnew[r] = cn;
      hnew[r] = f2bf(o_ * ftanh(cn));
    }
    *reinterpret_cast<f32x4*>(cout + pix * 64 + nf0) = cnew;
    short4 hv = make_short4(hnew[0], hnew[1], hnew[2], hnew[3]);
    *reinterpret_cast<short4*>(hout + pix * 64 + nf0) = hv;
  }
}

// head: y[b,t,pix] = b_cnn + sum_{f,tap} wc2[tap][f] * h[pix+tap][f]
__global__ __launch_bounds__(256) void head_k(const short* __restrict__ h,
                                              const float* __restrict__ wc2,
                                              const float* __restrict__ bc,
                                              float* __restrict__ yout, int t) {
  const int tid = blockIdx.x * 256 + threadIdx.x;  // 131072 threads
  const int pix = tid & 4095;
  const int b = tid >> 12;
  const int x0 = pix & 63, y0 = pix >> 6;
  float acc = bc[0];
  const short* hb = h + (size_t)b * (HW * 64);
#pragma unroll
  for (int tap = 0; tap < 9; ++tap) {
    const int yy = y0 + tap / 3 - 1, xx = x0 + (tap % 3) - 1;
    if (yy < 0 || yy > 63 || xx < 0 || xx > 63) continue;
    const short* hp = hb + (yy * 64 + xx) * 64;
    const float* wp = wc2 + tap * 64;
#pragma unroll
    for (int f8 = 0; f8 < 8; ++f8) {
      bf16x8 v = *reinterpret_cast<const bf16x8*>(hp + f8 * 8);
#pragma unroll
      for (int j = 0; j < 8; ++j) acc = fmaf(wp[f8 * 8 + j], bf2f(v[j]), acc);
    }
  }
  yout[(size_t)(b * 12 + t) * HW + pix] = acc;
}

// encoder-vector output: transpose [b][pix][ch] bf16 -> [b][ch][pix] f32
__global__ __launch_bounds__(256) void ev_out_k(const short* __restrict__ h,
                                                float* __restrict__ out) {
  __shared__ float tl[64][65];
  const int b = blockIdx.y, pg = blockIdx.x;
  const int p0 = pg * 64;
  {
    const int pixl = threadIdx.x >> 2, c0 = (threadIdx.x & 3) * 16;
    const short* hp = h + ((size_t)b * HW + p0 + pixl) * 64 + c0;
#pragma unroll
    for (int i = 0; i < 16; ++i) tl[pixl][c0 + i] = bf2f(hp[i]);
  }
  __syncthreads();
  {
    const int ch = threadIdx.x >> 2, q0 = (threadIdx.x & 3) * 16;
    float* op = out + ((size_t)b * 64 + ch) * (size_t)HW + p0 + q0;
#pragma unroll
    for (int i = 0; i < 16; ++i) op[i] = tl[q0 + i][ch];
  }
}

// W_enc [256][65][3][3] f32 -> Wh bf16 [9][256][64] (h part) + wx f32 [256][9]
__global__ __launch_bounds__(256) void reo_enc_k(const float* __restrict__ src,
                                                 short* __restrict__ Wh,
                                                 float* __restrict__ wx) {
  const int idx = blockIdx.x * 256 + threadIdx.x;
  if (idx < 9 * 256 * 64) {
    const int tap = idx >> 14, oc = (idx >> 6) & 255, c = idx & 63;
    Wh[idx] = f2bf(src[(oc * 65 + (c + 1)) * 9 + tap]);
  }
  if (idx < 256 * 9) {
    const int oc = idx / 9, tap = idx % 9;
    wx[idx] = src[(oc * 65 + 0) * 9 + tap];
  }
}

// W_dec [256][128][3][3] f32 -> Wx bf16 [9][256][64], Wsum bf16 (x+h parts)
__global__ __launch_bounds__(256) void reo_dec_k(const float* __restrict__ src,
                                                 short* __restrict__ Wx,
                                                 short* __restrict__ Ws) {
  const int idx = blockIdx.x * 256 + threadIdx.x;
  if (idx >= 9 * 256 * 64) return;
  const int tap = idx >> 14, oc = (idx >> 6) & 255, c = idx & 63;
  const float a = src[(oc * 128 + c) * 9 + tap];
  const float b = src[(oc * 128 + 64 + c) * 9 + tap];
  Wx[idx] = f2bf(a);
  Ws[idx] = f2bf(a + b);
}

// W_cnn [64][9] f32 -> [9][64] f32
__global__ __launch_bounds__(256) void reo_cnn_k(const float* __restrict__ src,
                                                 float* __restrict__ wc2) {
  const int idx = blockIdx.x * 256 + threadIdx.x;
  if (idx >= 576) return;
  wc2[idx] = src[(idx % 64) * 9 + (idx / 64)];
}

extern "C" void kernel_launch(void* const* d_in, const int* in_sizes, int n_in,
                              void* d_out, int out_size, void* d_ws, size_t ws_size,
                              hipStream_t stream) {
  const float* x = (const float*)d_in[0];       // [32,12,1,64,64] f32
  const float* W_enc = (const float*)d_in[2];
  const float* b_enc = (const float*)d_in[3];
  const float* W_dec = (const float*)d_in[4];
  const float* b_dec = (const float*)d_in[5];
  const float* W_cnn = (const float*)d_in[6];
  const float* b_cnn = (const float*)d_in[7];
  float* out = (float*)d_out;
  float* out_y = out;                 // [32][12][4096]
  float* out_ev = out + 1572864;      // [32][64][4096]

  float* ws = (float*)d_ws;
  float* cA = ws;                                // 8388608 f
  float* cB = cA + 8388608;                      // 8388608 f
  short* hA = (short*)(cB + 8388608);            // 8388608 sh
  short* hB = hA + 8388608;                      // 8388608 sh
  short* WEh = hB + 8388608;                     // 147456 sh
  short* WDx = WEh + 147456;                     // 147456 sh
  short* WDs = WDx + 147456;                     // 147456 sh
  float* wx = (float*)(WDs + 147456);            // 2304 f
  float* wc2 = wx + 2304;                        // 576 f  (~101 MB total)

  reo_enc_k<<<(147456 + 255) / 256, 256, 0, stream>>>(W_enc, WEh, wx);
  reo_dec_k<<<(147456 + 255) / 256, 256, 0, stream>>>(W_dec, WDx, WDs);
  reo_cnn_k<<<3, 256, 0, stream>>>(W_cnn, wc2);

  hipMemsetAsync(hA, 0, 8388608 * sizeof(short), stream);
  hipMemsetAsync(cA, 0, 8388608 * sizeof(float), stream);

  dim3 gridL(32, 64), blkL(256);   // x=batch (XCD-fast), y=row; 1 row/block
  dim3 gridE(64, 32), blkE(256);
  short *ha = hA, *hb = hB;
  float *ca = cA, *cb = cB;

  // ---- encoder ----
  for (int t = 0; t < 12; ++t) {
    lstm_mfma_k<true><<<gridL, blkL, 0, stream>>>(ha, WEh, wx, x + t * HW,
                                                  b_enc, ca, hb, cb);
    { short* tm = ha; ha = hb; hb = tm; }
    { float* tm = ca; ca = cb; cb = tm; }
  }
  // ha = h_enc -> output 1 (transposed to [b][ch][pix] f32)
  ev_out_k<<<gridE, blkE, 0, stream>>>(ha, out_ev);

  // fresh zero c for decoder
  hipMemsetAsync(cb, 0, 8388608 * sizeof(float), stream);
  { float* tm = ca; ca = cb; cb = tm; }  // ca = zeroed c

  // ---- decoder ----
  for (int t = 0; t < 12; ++t) {
    lstm_mfma_k<false><<<gridL, blkL, 0, stream>>>(
        ha, (t == 0) ? WDx : WDs, nullptr, nullptr, b_dec, ca, hb, cb);
    { short* tm = ha; ha = hb; hb = tm; }
    { float* tm = ca; ca = cb; cb = tm; }
    head_k<<<512, 256, 0, stream>>>(ha, wc2, b_cnn, out_y, t);
  }
}

// Round 4
// 2277.600 us; speedup vs baseline: 1.8977x; 1.2332x over previous
//
#include <hip/hip_runtime.h>
#include <hip/hip_bf16.h>

// EncoderDecoderConvLSTM — Round 15: R12 structure, LDS cut for 2 blocks/CU.
// Occupancy bins on gfx950: <=128 total regs/wave -> 4 waves/SIMD; 129-256 ->
// 2. R12's all-LDS wave measured exactly 128 regs (acc in AGPR) but 100 KB
// LDS allowed only 1 block (8 waves/CU). R14's global-A wave bloated to 176
// regs (compiler pipelining) -> 2/SIMD bin, ~4 waves/CU resident, latency-
// bound at 122 us. Now: R12 verbatim but As single-buffered 32 KB (2
// barriers/tap; co-resident block hides barrier stalls), LDS 67.5 KB -> 2
// blocks/CU = 16 waves/CU. Grid (batch-fast, row-slow) keeps halo L2-local
// (R14-verified: FETCH 26 MB). W pre-swizzled so linear stage = swizzled LDS.
// h [b][4096][64] bf16; c f32; W [9][256][64] bf16 swizzled; fused epilogue.

#define HW 4096
#define NF 64

typedef __attribute__((ext_vector_type(8))) short bf16x8;
typedef __attribute__((ext_vector_type(4))) float f32x4;

__device__ __forceinline__ float fsig(float v) {
  return __builtin_amdgcn_rcpf(1.f + __expf(-v));
}
__device__ __forceinline__ float ftanh(float v) {
  float vc = fminf(fmaxf(v, -15.f), 15.f);
  float e = __expf(2.f * vc);
  return (e - 1.f) * __builtin_amdgcn_rcpf(e + 1.f);
}
__device__ __forceinline__ float bf2f(short s) {
  union { unsigned u; float f; } a;
  a.u = ((unsigned)(unsigned short)s) << 16;
  return a.f;
}
__device__ __forceinline__ short f2bf(float f) {  // RNE
  union { float f; unsigned u; } a;
  a.f = f;
  unsigned r = (a.u + 0x7fff + ((a.u >> 16) & 1)) >> 16;
  return (short)r;
}

// 8 waves: (wv&3) = nf-slice (16 oc per gate), (wv>>2) = output row y0+0/1.
// LDS: As[16384] single-buffer per-tap weights (pre-swizzled ^(oc&7)<<3),
// Bs[4][66][64] halo (slot s holds px=s-1; slots 0/65 zero; ^(s&7)<<3),
// xs[4][64]. 2 barriers/tap; T14 issue-early/write-late A prefetch.
template <bool HAS_X>
__global__ __launch_bounds__(512) void lstm_mfma_k(
    const short* __restrict__ hin,   // [32][4096][64] bf16
    const short* __restrict__ W,     // [9][256][64] bf16, pre-swizzled
    const float* __restrict__ wx,    // [256][9] f32 (x-part) or null
    const float* __restrict__ xpl,   // x + t*HW (batch stride 12*HW) or null
    const float* __restrict__ bias,  // [256] f32
    const float* __restrict__ cin,   // [32][4096][64] f32
    short* __restrict__ hout,
    float* __restrict__ cout) {
  const int b = blockIdx.x;        // 0..31 batch (fast dim -> XCD spread)
  const int y0 = blockIdx.y * 2;   // output rows y0, y0+1
  const int tid = threadIdx.x;
  const int lane = tid & 63;
  const int wv = tid >> 6;         // 0..7
  const int wnf = wv & 3;          // nf slice
  const int wrow = wv >> 2;        // 0..1 output row
  const int col = lane & 15;
  const int quad = lane >> 4;

  __shared__ short As[16384];      // 32 KB, one tap
  __shared__ short Bs[4 * 66 * 64];
  __shared__ float xs[4][64];

  const short* hb = hin + (size_t)b * (HW * 64);
  // ---- stage B halo: rows y0-1..y0+2, 4 x 64 px x 64 ch, swizzled ----
#pragma unroll
  for (int i = 0; i < 4; ++i) {
    const int t = tid + i * 512;           // 0..2047
    const int r = t >> 9;                  // 0..3
    const int c = t & 511;
    const int px = c >> 3, ch0 = (c & 7) * 8;
    const int py = y0 - 1 + r;
    bf16x8 v = {0, 0, 0, 0, 0, 0, 0, 0};
    if (py >= 0 && py < 64)
      v = *reinterpret_cast<const bf16x8*>(hb + ((py * 64 + px) * 64) + ch0);
    *reinterpret_cast<bf16x8*>(
        &Bs[(((r * 66 + px + 1) * 64) + ch0) ^ ((((px + 1) & 7)) << 3)]) = v;
  }
  if (tid < 64) {  // zero x-border slots 0 and 65: 4 rows x 2 x 8 chunks
    const int r = tid >> 4;
    const int s = ((tid >> 3) & 1) * 65;
    const int ch0 = (tid & 7) * 8;
    bf16x8 z = {0, 0, 0, 0, 0, 0, 0, 0};
    *reinterpret_cast<bf16x8*>(
        &Bs[(((r * 66 + s) * 64) + ch0) ^ ((s & 7) << 3)]) = z;
  }
  // ---- stage A tap 0 (linear copy of pre-swizzled W) ----
#pragma unroll
  for (int i = 0; i < 4; ++i) {
    const int q = tid + i * 512;   // 16B chunk 0..2047
    *reinterpret_cast<bf16x8*>(&As[q * 8]) =
        *reinterpret_cast<const bf16x8*>(W + q * 8);
  }
  if (HAS_X) {
    if (tid < 256) {
      const float* xb = xpl + (size_t)b * (12 * HW);
      const int r = tid >> 6, cx = tid & 63;
      const int py = y0 - 1 + r;
      xs[r][cx] = (py >= 0 && py < 64) ? xb[py * 64 + cx] : 0.f;
    }
  }
  __syncthreads();

  f32x4 acc[4][4];  // [gate][n-tile]
#pragma unroll
  for (int g = 0; g < 4; ++g) {
    const int oc0 = g * 64 + wnf * 16 + quad * 4;
#pragma unroll
    for (int nt = 0; nt < 4; ++nt)
#pragma unroll
      for (int r = 0; r < 4; ++r) acc[g][nt][r] = bias[oc0 + r];
  }

  if (HAS_X) {
#pragma unroll
    for (int nt = 0; nt < 4; ++nt) {
      const int px = nt * 16 + col;
#pragma unroll
      for (int tap = 0; tap < 9; ++tap) {
        const int pxx = px + (tap % 3) - 1;
        const float xv =
            (pxx >= 0 && pxx < 64) ? xs[wrow + tap / 3][pxx] : 0.f;
#pragma unroll
        for (int g = 0; g < 4; ++g) {
          const int oc0 = g * 64 + wnf * 16 + quad * 4;
#pragma unroll
          for (int r = 0; r < 4; ++r)
            acc[g][nt][r] = fmaf(xv, wx[(oc0 + r) * 9 + tap], acc[g][nt][r]);
        }
      }
    }
  }

  // ---- main loop: per tap, A single-buffered in LDS, B resident ----
  const int axr = (col & 7) << 3;
#pragma unroll
  for (int tap = 0; tap < 9; ++tap) {
    bf16x8 anx[4];
    if (tap < 8) {  // issue next tap's A loads early (T14)
#pragma unroll
      for (int i = 0; i < 4; ++i) {
        const int q = tid + i * 512;
        anx[i] = *reinterpret_cast<const bf16x8*>(W + (tap + 1) * 16384 + q * 8);
      }
    }
    const int hr = wrow + tap / 3;          // halo row 0..3
    const int sb = col + (tap % 3);         // slot for nt=0 (= px+dx+1)
    const int sx = (sb & 7) << 3;
#pragma unroll
    for (int kc = 0; kc < 2; ++kc) {
      const int chb = kc * 32 + quad * 8;
      const int abase = (((wnf * 16 + col) * 64) + chb) ^ axr;
      const int bbase = (((hr * 66 + sb) * 64) + chb) ^ sx;
      bf16x8 a[4], bfr[4];
#pragma unroll
      for (int g = 0; g < 4; ++g)
        a[g] = *reinterpret_cast<const bf16x8*>(&As[abase + g * 4096]);
#pragma unroll
      for (int nt = 0; nt < 4; ++nt)
        bfr[nt] = *reinterpret_cast<const bf16x8*>(&Bs[bbase + nt * 1024]);
      __builtin_amdgcn_s_setprio(1);
#pragma unroll
      for (int g = 0; g < 4; ++g)
#pragma unroll
        for (int nt = 0; nt < 4; ++nt)
          acc[g][nt] = __builtin_amdgcn_mfma_f32_16x16x32_bf16(a[g], bfr[nt],
                                                               acc[g][nt], 0, 0, 0);
      __builtin_amdgcn_s_setprio(0);
    }
    if (tap < 8) {  // all waves done reading As -> overwrite with next tap
      __syncthreads();
#pragma unroll
      for (int i = 0; i < 4; ++i) {
        const int q = tid + i * 512;
        *reinterpret_cast<bf16x8*>(&As[q * 8]) = anx[i];
      }
      __syncthreads();
    }
  }

  // ---- in-register epilogue ----
  const int nf0 = wnf * 16 + quad * 4;
  const int y = y0 + wrow;
#pragma unroll
  for (int nt = 0; nt < 4; ++nt) {
    const int px = nt * 16 + col;
    const size_t pix = (size_t)b * HW + y * 64 + px;
    f32x4 cold = *reinterpret_cast<const f32x4*>(cin + pix * 64 + nf0);
    f32x4 cnew;
    short hnew[4];
#pragma unroll
    for (int r = 0; r < 4; ++r) {
      float i_ = fsig(acc[0][nt][r]);
      float f_ = fsig(acc[1][nt][r]);
      float o_ = fsig(acc[2][nt][r]);
      float g_ = ftanh(acc[3][nt][r]);
      float cn = fmaf(f_, cold[r], i_ * g_);
      cnew[r] = cn;
      hnew[r] = f2bf(o_ * ftanh(cn));
    }
    *reinterpret_cast<f32x4*>(cout + pix * 64 + nf0) = cnew;
    short4 hv = make_short4(hnew[0], hnew[1], hnew[2], hnew[3]);
    *reinterpret_cast<short4*>(hout + pix * 64 + nf0) = hv;
  }
}

// head: y[b,t,pix] = b_cnn + sum_{f,tap} wc2[tap][f] * h[pix+tap][f]
__global__ __launch_bounds__(256) void head_k(const short* __restrict__ h,
                                              const float* __restrict__ wc2,
                                              const float* __restrict__ bc,
                                              float* __restrict__ yout, int t) {
  const int tid = blockIdx.x * 256 + threadIdx.x;  // 131072 threads
  const int pix = tid & 4095;
  const int b = tid >> 12;
  const int x0 = pix & 63, y0 = pix >> 6;
  float acc = bc[0];
  const short* hb = h + (size_t)b * (HW * 64);
#pragma unroll
  for (int tap = 0; tap < 9; ++tap) {
    const int yy = y0 + tap / 3 - 1, xx = x0 + (tap % 3) - 1;
    if (yy < 0 || yy > 63 || xx < 0 || xx > 63) continue;
    const short* hp = hb + (yy * 64 + xx) * 64;
    const float* wp = wc2 + tap * 64;
#pragma unroll
    for (int f8 = 0; f8 < 8; ++f8) {
      bf16x8 v = *reinterpret_cast<const bf16x8*>(hp + f8 * 8);
#pragma unroll
      for (int j = 0; j < 8; ++j) acc = fmaf(wp[f8 * 8 + j], bf2f(v[j]), acc);
    }
  }
  yout[(size_t)(b * 12 + t) * HW + pix] = acc;
}

// encoder-vector output: transpose [b][pix][ch] bf16 -> [b][ch][pix] f32
__global__ __launch_bounds__(256) void ev_out_k(const short* __restrict__ h,
                                                float* __restrict__ out) {
  __shared__ float tl[64][65];
  const int b = blockIdx.y, pg = blockIdx.x;
  const int p0 = pg * 64;
  {
    const int pixl = threadIdx.x >> 2, c0 = (threadIdx.x & 3) * 16;
    const short* hp = h + ((size_t)b * HW + p0 + pixl) * 64 + c0;
#pragma unroll
    for (int i = 0; i < 16; ++i) tl[pixl][c0 + i] = bf2f(hp[i]);
  }
  __syncthreads();
  {
    const int ch = threadIdx.x >> 2, q0 = (threadIdx.x & 3) * 16;
    float* op = out + ((size_t)b * 64 + ch) * (size_t)HW + p0 + q0;
#pragma unroll
    for (int i = 0; i < 16; ++i) op[i] = tl[q0 + i][ch];
  }
}

// W_enc [256][65][3][3] f32 -> Wh bf16 [9][256][64] SWIZZLED (h part)
// + wx f32 [256][9]. Swizzle: short_idx_in_tap = (oc*64+c) ^ ((oc&7)<<3),
// so a linear global->LDS copy lands in the read-side swizzled layout.
__global__ __launch_bounds__(256) void reo_enc_k(const float* __restrict__ src,
                                                 short* __restrict__ Wh,
                                                 float* __restrict__ wx) {
  const int idx = blockIdx.x * 256 + threadIdx.x;
  if (idx < 9 * 256 * 64) {
    const int tap = idx >> 14, oc = (idx >> 6) & 255, c = idx & 63;
    const int dst = tap * 16384 + (((oc * 64) + c) ^ ((oc & 7) << 3));
    Wh[dst] = f2bf(src[(oc * 65 + (c + 1)) * 9 + tap]);
  }
  if (idx < 256 * 9) {
    const int oc = idx / 9, tap = idx % 9;
    wx[idx] = src[(oc * 65 + 0) * 9 + tap];
  }
}

// W_dec [256][128][3][3] f32 -> Wx bf16 [9][256][64], Wsum bf16, both swizzled
__global__ __launch_bounds__(256) void reo_dec_k(const float* __restrict__ src,
                                                 short* __restrict__ Wx,
                                                 short* __restrict__ Ws) {
  const int idx = blockIdx.x * 256 + threadIdx.x;
  if (idx >= 9 * 256 * 64) return;
  const int tap = idx >> 14, oc = (idx >> 6) & 255, c = idx & 63;
  const int dst = tap * 16384 + (((oc * 64) + c) ^ ((oc & 7) << 3));
  const float a = src[(oc * 128 + c) * 9 + tap];
  const float b = src[(oc * 128 + 64 + c) * 9 + tap];
  Wx[dst] = f2bf(a);
  Ws[dst] = f2bf(a + b);
}

// W_cnn [64][9] f32 -> [9][64] f32
__global__ __launch_bounds__(256) void reo_cnn_k(const float* __restrict__ src,
                                                 float* __restrict__ wc2) {
  const int idx = blockIdx.x * 256 + threadIdx.x;
  if (idx >= 576) return;
  wc2[idx] = src[(idx % 64) * 9 + (idx / 64)];
}

extern "C" void kernel_launch(void* const* d_in, const int* in_sizes, int n_in,
                              void* d_out, int out_size, void* d_ws, size_t ws_size,
                              hipStream_t stream) {
  const float* x = (const float*)d_in[0];       // [32,12,1,64,64] f32
  const float* W_enc = (const float*)d_in[2];
  const float* b_enc = (const float*)d_in[3];
  const float* W_dec = (const float*)d_in[4];
  const float* b_dec = (const float*)d_in[5];
  const float* W_cnn = (const float*)d_in[6];
  const float* b_cnn = (const float*)d_in[7];
  float* out = (float*)d_out;
  float* out_y = out;                 // [32][12][4096]
  float* out_ev = out + 1572864;      // [32][64][4096]

  float* ws = (float*)d_ws;
  float* cA = ws;                                // 8388608 f
  float* cB = cA + 8388608;                      // 8388608 f
  short* hA = (short*)(cB + 8388608);            // 8388608 sh
  short* hB = hA + 8388608;                      // 8388608 sh
  short* WEh = hB + 8388608;                     // 147456 sh
  short* WDx = WEh + 147456;                     // 147456 sh
  short* WDs = WDx + 147456;                     // 147456 sh
  float* wx = (float*)(WDs + 147456);            // 2304 f
  float* wc2 = wx + 2304;                        // 576 f  (~101 MB total)

  reo_enc_k<<<(147456 + 255) / 256, 256, 0, stream>>>(W_enc, WEh, wx);
  reo_dec_k<<<(147456 + 255) / 256, 256, 0, stream>>>(W_dec, WDx, WDs);
  reo_cnn_k<<<3, 256, 0, stream>>>(W_cnn, wc2);

  hipMemsetAsync(hA, 0, 8388608 * sizeof(short), stream);
  hipMemsetAsync(cA, 0, 8388608 * sizeof(float), stream);

  dim3 gridL(32, 32), blkL(512);   // x=batch (XCD-fast), y=row-pair
  dim3 gridE(64, 32), blkE(256);
  short *ha = hA, *hb = hB;
  float *ca = cA, *cb = cB;

  // ---- encoder ----
  for (int t = 0; t < 12; ++t) {
    lstm_mfma_k<true><<<gridL, blkL, 0, stream>>>(ha, WEh, wx, x + t * HW,
                                                  b_enc, ca, hb, cb);
    { short* tm = ha; ha = hb; hb = tm; }
    { float* tm = ca; ca = cb; cb = tm; }
  }
  // ha = h_enc -> output 1 (transposed to [b][ch][pix] f32)
  ev_out_k<<<gridE, blkE, 0, stream>>>(ha, out_ev);

  // fresh zero c for decoder
  hipMemsetAsync(cb, 0, 8388608 * sizeof(float), stream);
  { float* tm = ca; ca = cb; cb = tm; }  // ca = zeroed c

  // ---- decoder ----
  for (int t = 0; t < 12; ++t) {
    lstm_mfma_k<false><<<gridL, blkL, 0, stream>>>(
        ha, (t == 0) ? WDx : WDs, nullptr, nullptr, b_dec, ca, hb, cb);
    { short* tm = ha; ha = hb; hb = tm; }
    { float* tm = ca; ca = cb; cb = tm; }
    head_k<<<512, 256, 0, stream>>>(ha, wc2, b_cnn, out_y, t);
  }
}

// Round 5
// 2210.580 us; speedup vs baseline: 1.9552x; 1.0303x over previous
//
#include <hip/hip_runtime.h>
#include <hip/hip_bf16.h>

// EncoderDecoderConvLSTM — Round 16: nt-split waves -> 4 waves/SIMD bin.
// R12/R15 invariant: 64 acc-AGPR/wave forces total regs ~192 -> 2 waves/SIMD
// (512-reg pool) AND compiler spills past its 128-VGPR cap (WRITE 170 MB vs
// 48 real). Fix: halve per-wave output. 8 waves/block, 1 row; wave =
// (wnf 0..3, whalf 0..1): 4 gates x 2 px-tiles -> acc[4][2] = 32 AGPR,
// ~90 VGPR -> total ~122 <= 128 -> 4 waves/SIMD. LDS 57.5 KB (As 32 KB
// single-buffered per-tap + 3-row swizzled halo 24.75 KB) -> 2 blocks/CU
// -> 16 waves/CU; co-resident block hides per-tap barriers. Batch-fast grid
// keeps halo L2-local (R14: FETCH 26 MB). W pre-swizzled for linear staging.
// h [b][4096][64] bf16; c f32; W [9][256][64] bf16 swizzled; fused epilogue.

#define HW 4096
#define NF 64

typedef __attribute__((ext_vector_type(8))) short bf16x8;
typedef __attribute__((ext_vector_type(4))) float f32x4;

__device__ __forceinline__ float fsig(float v) {
  return __builtin_amdgcn_rcpf(1.f + __expf(-v));
}
__device__ __forceinline__ float ftanh(float v) {
  float vc = fminf(fmaxf(v, -15.f), 15.f);
  float e = __expf(2.f * vc);
  return (e - 1.f) * __builtin_amdgcn_rcpf(e + 1.f);
}
__device__ __forceinline__ float bf2f(short s) {
  union { unsigned u; float f; } a;
  a.u = ((unsigned)(unsigned short)s) << 16;
  return a.f;
}
__device__ __forceinline__ short f2bf(float f) {  // RNE
  union { float f; unsigned u; } a;
  a.f = f;
  unsigned r = (a.u + 0x7fff + ((a.u >> 16) & 1)) >> 16;
  return (short)r;
}

// 8 waves: wnf = wv&3 (16-oc slice per gate), whalf = wv>>2 (px half).
// LDS: As[16384] single-buffer per-tap weights (pre-swizzled ^(oc&7)<<3),
// Bs[3][66][64] halo (slot s holds px=s-1; slots 0/65 zero; ^(s&7)<<3),
// xs[3][64]. 2 barriers/tap; T14 issue-early/write-late A prefetch.
template <bool HAS_X>
__global__ __launch_bounds__(512) void lstm_mfma_k(
    const short* __restrict__ hin,   // [32][4096][64] bf16
    const short* __restrict__ W,     // [9][256][64] bf16, pre-swizzled
    const float* __restrict__ wx,    // [256][9] f32 (x-part) or null
    const float* __restrict__ xpl,   // x + t*HW (batch stride 12*HW) or null
    const float* __restrict__ bias,  // [256] f32
    const float* __restrict__ cin,   // [32][4096][64] f32
    short* __restrict__ hout,
    float* __restrict__ cout) {
  const int b = blockIdx.x;        // 0..31 batch (fast dim -> XCD spread)
  const int y = blockIdx.y;        // 0..63 row   (same-b rows co-XCD)
  const int tid = threadIdx.x;
  const int lane = tid & 63;
  const int wv = tid >> 6;         // 0..7
  const int wnf = wv & 3;          // oc slice within each gate
  const int whalf = wv >> 2;       // 0..1 px half
  const int col = lane & 15;
  const int quad = lane >> 4;

  __shared__ short As[16384];      // 32 KB, one tap
  __shared__ short Bs[3 * 66 * 64];
  __shared__ float xs[3][64];

  const short* hb = hin + (size_t)b * (HW * 64);
  // ---- stage B halo: rows y-1..y+1, 3 x 64 px x 64 ch, swizzled ----
#pragma unroll
  for (int i = 0; i < 3; ++i) {
    const int t = tid + i * 512;           // 0..1535
    const int r = t >> 9;                  // 0..2
    const int c = t & 511;
    const int px = c >> 3, ch0 = (c & 7) * 8;
    const int py = y - 1 + r;
    bf16x8 v = {0, 0, 0, 0, 0, 0, 0, 0};
    if (py >= 0 && py < 64)
      v = *reinterpret_cast<const bf16x8*>(hb + ((py * 64 + px) * 64) + ch0);
    *reinterpret_cast<bf16x8*>(
        &Bs[(((r * 66 + px + 1) * 64) + ch0) ^ ((((px + 1) & 7)) << 3)]) = v;
  }
  if (tid < 48) {  // zero x-border slots 0 and 65: 3 rows x 2 x 8 chunks
    const int r = tid >> 4;
    const int s = ((tid >> 3) & 1) * 65;
    const int ch0 = (tid & 7) * 8;
    bf16x8 z = {0, 0, 0, 0, 0, 0, 0, 0};
    *reinterpret_cast<bf16x8*>(
        &Bs[(((r * 66 + s) * 64) + ch0) ^ ((s & 7) << 3)]) = z;
  }
  // ---- stage A tap 0 (linear copy of pre-swizzled W) ----
#pragma unroll
  for (int i = 0; i < 4; ++i) {
    const int q = tid + i * 512;   // 16B chunk 0..2047
    *reinterpret_cast<bf16x8*>(&As[q * 8]) =
        *reinterpret_cast<const bf16x8*>(W + q * 8);
  }
  if (HAS_X) {
    if (tid < 192) {
      const float* xb = xpl + (size_t)b * (12 * HW);
      const int r = tid >> 6, cx = tid & 63;
      const int py = y - 1 + r;
      xs[r][cx] = (py >= 0 && py < 64) ? xb[py * 64 + cx] : 0.f;
    }
  }
  __syncthreads();

  f32x4 acc[4][2];  // [gate][local n-tile]
#pragma unroll
  for (int g = 0; g < 4; ++g) {
    const int oc0 = g * 64 + wnf * 16 + quad * 4;
#pragma unroll
    for (int nt = 0; nt < 2; ++nt)
#pragma unroll
      for (int r = 0; r < 4; ++r) acc[g][nt][r] = bias[oc0 + r];
  }

  if (HAS_X) {
#pragma unroll
    for (int nt = 0; nt < 2; ++nt) {
      const int px = whalf * 32 + nt * 16 + col;
#pragma unroll
      for (int tap = 0; tap < 9; ++tap) {
        const int pxx = px + (tap % 3) - 1;
        const float xv = (pxx >= 0 && pxx < 64) ? xs[tap / 3][pxx] : 0.f;
#pragma unroll
        for (int g = 0; g < 4; ++g) {
          const int oc0 = g * 64 + wnf * 16 + quad * 4;
#pragma unroll
          for (int r = 0; r < 4; ++r)
            acc[g][nt][r] = fmaf(xv, wx[(oc0 + r) * 9 + tap], acc[g][nt][r]);
        }
      }
    }
  }

  // ---- main loop: per tap, A single-buffered in LDS, B resident ----
  const int axr = (col & 7) << 3;
#pragma unroll
  for (int tap = 0; tap < 9; ++tap) {
    bf16x8 anx[4];
    if (tap < 8) {  // issue next tap's A loads early (T14), hide under MFMA
#pragma unroll
      for (int i = 0; i < 4; ++i) {
        const int q = tid + i * 512;
        anx[i] = *reinterpret_cast<const bf16x8*>(W + (tap + 1) * 16384 + q * 8);
      }
    }
    const int hr = tap / 3;                 // halo row 0..2
    const int sb = col + (tap % 3);         // slot base (= px+dx+1 - offsets)
    const int sx = (sb & 7) << 3;           // +16/+32 don't change low 3 bits
    const int srow = (hr * 66 + whalf * 32 + sb) * 64;
#pragma unroll
    for (int kc = 0; kc < 2; ++kc) {
      const int chb = kc * 32 + quad * 8;
      const int abase = (((wnf * 16 + col) * 64) + chb) ^ axr;
      const int bbase = (srow + chb) ^ sx;
      bf16x8 a[4], bfr[2];
#pragma unroll
      for (int g = 0; g < 4; ++g)
        a[g] = *reinterpret_cast<const bf16x8*>(&As[abase + g * 4096]);
#pragma unroll
      for (int nt = 0; nt < 2; ++nt)
        bfr[nt] = *reinterpret_cast<const bf16x8*>(&Bs[bbase + nt * 1024]);
      __builtin_amdgcn_s_setprio(1);
#pragma unroll
      for (int g = 0; g < 4; ++g)
#pragma unroll
        for (int nt = 0; nt < 2; ++nt)
          acc[g][nt] = __builtin_amdgcn_mfma_f32_16x16x32_bf16(a[g], bfr[nt],
                                                               acc[g][nt], 0, 0, 0);
      __builtin_amdgcn_s_setprio(0);
    }
    if (tap < 8) {  // all waves done reading As -> overwrite with next tap
      __syncthreads();
#pragma unroll
      for (int i = 0; i < 4; ++i) {
        const int q = tid + i * 512;
        *reinterpret_cast<bf16x8*>(&As[q * 8]) = anx[i];
      }
      __syncthreads();
    }
  }

  // ---- in-register epilogue ----
  const int nf0 = wnf * 16 + quad * 4;
#pragma unroll
  for (int nt = 0; nt < 2; ++nt) {
    const int px = whalf * 32 + nt * 16 + col;
    const size_t pix = (size_t)b * HW + y * 64 + px;
    f32x4 cold = *reinterpret_cast<const f32x4*>(cin + pix * 64 + nf0);
    f32x4 cnew;
    short hnew[4];
#pragma unroll
    for (int r = 0; r < 4; ++r) {
      float i_ = fsig(acc[0][nt][r]);
      float f_ = fsig(acc[1][nt][r]);
      float o_ = fsig(acc[2][nt][r]);
      float g_ = ftanh(acc[3][nt][r]);
      float cn = fmaf(f_, cold[r], i_ * g_);
      cnew[r] = cn;
      hnew[r] = f2bf(o_ * ftanh(cn));
    }
    *reinterpret_cast<f32x4*>(cout + pix * 64 + nf0) = cnew;
    short4 hv = make_short4(hnew[0], hnew[1], hnew[2], hnew[3]);
    *reinterpret_cast<short4*>(hout + pix * 64 + nf0) = hv;
  }
}

// head: y[b,t,pix] = b_cnn + sum_{f,tap} wc2[tap][f] * h[pix+tap][f]
__global__ __launch_bounds__(256) void head_k(const short* __restrict__ h,
                                              const float* __restrict__ wc2,
                                              const float* __restrict__ bc,
                                              float* __restrict__ yout, int t) {
  const int tid = blockIdx.x * 256 + threadIdx.x;  // 131072 threads
  const int pix = tid & 4095;
  const int b = tid >> 12;
  const int x0 = pix & 63, y0 = pix >> 6;
  float acc = bc[0];
  const short* hb = h + (size_t)b * (HW * 64);
#pragma unroll
  for (int tap = 0; tap < 9; ++tap) {
    const int yy = y0 + tap / 3 - 1, xx = x0 + (tap % 3) - 1;
    if (yy < 0 || yy > 63 || xx < 0 || xx > 63) continue;
    const short* hp = hb + (yy * 64 + xx) * 64;
    const float* wp = wc2 + tap * 64;
#pragma unroll
    for (int f8 = 0; f8 < 8; ++f8) {
      bf16x8 v = *reinterpret_cast<const bf16x8*>(hp + f8 * 8);
#pragma unroll
      for (int j = 0; j < 8; ++j) acc = fmaf(wp[f8 * 8 + j], bf2f(v[j]), acc);
    }
  }
  yout[(size_t)(b * 12 + t) * HW + pix] = acc;
}

// encoder-vector output: transpose [b][pix][ch] bf16 -> [b][ch][pix] f32
__global__ __launch_bounds__(256) void ev_out_k(const short* __restrict__ h,
                                                float* __restrict__ out) {
  __shared__ float tl[64][65];
  const int b = blockIdx.y, pg = blockIdx.x;
  const int p0 = pg * 64;
  {
    const int pixl = threadIdx.x >> 2, c0 = (threadIdx.x & 3) * 16;
    const short* hp = h + ((size_t)b * HW + p0 + pixl) * 64 + c0;
#pragma unroll
    for (int i = 0; i < 16; ++i) tl[pixl][c0 + i] = bf2f(hp[i]);
  }
  __syncthreads();
  {
    const int ch = threadIdx.x >> 2, q0 = (threadIdx.x & 3) * 16;
    float* op = out + ((size_t)b * 64 + ch) * (size_t)HW + p0 + q0;
#pragma unroll
    for (int i = 0; i < 16; ++i) op[i] = tl[q0 + i][ch];
  }
}

// W_enc [256][65][3][3] f32 -> Wh bf16 [9][256][64] SWIZZLED (h part)
// + wx f32 [256][9]. Swizzle: short_idx_in_tap = (oc*64+c) ^ ((oc&7)<<3),
// so a linear global->LDS copy lands in the read-side swizzled layout.
__global__ __launch_bounds__(256) void reo_enc_k(const float* __restrict__ src,
                                                 short* __restrict__ Wh,
                                                 float* __restrict__ wx) {
  const int idx = blockIdx.x * 256 + threadIdx.x;
  if (idx < 9 * 256 * 64) {
    const int tap = idx >> 14, oc = (idx >> 6) & 255, c = idx & 63;
    const int dst = tap * 16384 + (((oc * 64) + c) ^ ((oc & 7) << 3));
    Wh[dst] = f2bf(src[(oc * 65 + (c + 1)) * 9 + tap]);
  }
  if (idx < 256 * 9) {
    const int oc = idx / 9, tap = idx % 9;
    wx[idx] = src[(oc * 65 + 0) * 9 + tap];
  }
}

// W_dec [256][128][3][3] f32 -> Wx bf16 [9][256][64], Wsum bf16, both swizzled
__global__ __launch_bounds__(256) void reo_dec_k(const float* __restrict__ src,
                                                 short* __restrict__ Wx,
                                                 short* __restrict__ Ws) {
  const int idx = blockIdx.x * 256 + threadIdx.x;
  if (idx >= 9 * 256 * 64) return;
  const int tap = idx >> 14, oc = (idx >> 6) & 255, c = idx & 63;
  const int dst = tap * 16384 + (((oc * 64) + c) ^ ((oc & 7) << 3));
  const float a = src[(oc * 128 + c) * 9 + tap];
  const float b = src[(oc * 128 + 64 + c) * 9 + tap];
  Wx[dst] = f2bf(a);
  Ws[dst] = f2bf(a + b);
}

// W_cnn [64][9] f32 -> [9][64] f32
__global__ __launch_bounds__(256) void reo_cnn_k(const float* __restrict__ src,
                                                 float* __restrict__ wc2) {
  const int idx = blockIdx.x * 256 + threadIdx.x;
  if (idx >= 576) return;
  wc2[idx] = src[(idx % 64) * 9 + (idx / 64)];
}

extern "C" void kernel_launch(void* const* d_in, const int* in_sizes, int n_in,
                              void* d_out, int out_size, void* d_ws, size_t ws_size,
                              hipStream_t stream) {
  const float* x = (const float*)d_in[0];       // [32,12,1,64,64] f32
  const float* W_enc = (const float*)d_in[2];
  const float* b_enc = (const float*)d_in[3];
  const float* W_dec = (const float*)d_in[4];
  const float* b_dec = (const float*)d_in[5];
  const float* W_cnn = (const float*)d_in[6];
  const float* b_cnn = (const float*)d_in[7];
  float* out = (float*)d_out;
  float* out_y = out;                 // [32][12][4096]
  float* out_ev = out + 1572864;      // [32][64][4096]

  float* ws = (float*)d_ws;
  float* cA = ws;                                // 8388608 f
  float* cB = cA + 8388608;                      // 8388608 f
  short* hA = (short*)(cB + 8388608);            // 8388608 sh
  short* hB = hA + 8388608;                      // 8388608 sh
  short* WEh = hB + 8388608;                     // 147456 sh
  short* WDx = WEh + 147456;                     // 147456 sh
  short* WDs = WDx + 147456;                     // 147456 sh
  float* wx = (float*)(WDs + 147456);            // 2304 f
  float* wc2 = wx + 2304;                        // 576 f  (~101 MB total)

  reo_enc_k<<<(147456 + 255) / 256, 256, 0, stream>>>(W_enc, WEh, wx);
  reo_dec_k<<<(147456 + 255) / 256, 256, 0, stream>>>(W_dec, WDx, WDs);
  reo_cnn_k<<<3, 256, 0, stream>>>(W_cnn, wc2);

  hipMemsetAsync(hA, 0, 8388608 * sizeof(short), stream);
  hipMemsetAsync(cA, 0, 8388608 * sizeof(float), stream);

  dim3 gridL(32, 64), blkL(512);   // x=batch (XCD-fast), y=row; 1 row/block
  dim3 gridE(64, 32), blkE(256);
  short *ha = hA, *hb = hB;
  float *ca = cA, *cb = cB;

  // ---- encoder ----
  for (int t = 0; t < 12; ++t) {
    lstm_mfma_k<true><<<gridL, blkL, 0, stream>>>(ha, WEh, wx, x + t * HW,
                                                  b_enc, ca, hb, cb);
    { short* tm = ha; ha = hb; hb = tm; }
    { float* tm = ca; ca = cb; cb = tm; }
  }
  // ha = h_enc -> output 1 (transposed to [b][ch][pix] f32)
  ev_out_k<<<gridE, blkE, 0, stream>>>(ha, out_ev);

  // fresh zero c for decoder
  hipMemsetAsync(cb, 0, 8388608 * sizeof(float), stream);
  { float* tm = ca; ca = cb; cb = tm; }  // ca = zeroed c

  // ---- decoder ----
  for (int t = 0; t < 12; ++t) {
    lstm_mfma_k<false><<<gridL, blkL, 0, stream>>>(
        ha, (t == 0) ? WDx : WDs, nullptr, nullptr, b_dec, ca, hb, cb);
    { short* tm = ha; ha = hb; hb = tm; }
    { float* tm = ca; ca = cb; cb = tm; }
    head_k<<<512, 256, 0, stream>>>(ha, wc2, b_cnn, out_y, t);
  }
}

// Round 7
// 1943.416 us; speedup vs baseline: 2.2240x; 1.1375x over previous
//
#include <hip/hip_runtime.h>
#include <hip/hip_bf16.h>

// EncoderDecoderConvLSTM — Round 17 (resubmit; R6 was an infra timeout).
// R16 lesson: VGPR_Count reports ARCH regs only; 112+32 AGPR = 144 > 128 ->
// still 2 waves/SIMD, Occ 21%. The 16 anx-prefetch VGPRs were the overage.
// Now ALL staging is DMA (global_load_lds, width 16): A as 2x16KB gate-pair
// ping-pong inside 32 KB (18 phases, DMA next half under current MFMA,
// barrier's implicit vmcnt(0) drain delivers it); B halo DMA'd from h stored
// PRE-SWIZZLED in global (epilogue stores h_sw[pix][ch^((px+1)&7)<<3]) so
// linear DMA = swizzled LDS; y-border rows redirect DMA src to a zero page.
// No staging VGPRs -> ~80 arch + 32 AGPR <= 128 -> 4 waves/SIMD; LDS 57.5 KB
// -> 2 blocks/CU = 16 waves/CU. head_k/ev_out_k un-swizzle on read.
// h_sw [b][4096][64] bf16; c f32; W [9][256][64] bf16 pre-swizzled (^(oc&7)<<3).

#define HW 4096
#define NF 64

typedef __attribute__((ext_vector_type(8))) short bf16x8;
typedef __attribute__((ext_vector_type(4))) float f32x4;

__device__ __forceinline__ float fsig(float v) {
  return __builtin_amdgcn_rcpf(1.f + __expf(-v));
}
__device__ __forceinline__ float ftanh(float v) {
  float vc = fminf(fmaxf(v, -15.f), 15.f);
  float e = __expf(2.f * vc);
  return (e - 1.f) * __builtin_amdgcn_rcpf(e + 1.f);
}
__device__ __forceinline__ float bf2f(short s) {
  union { unsigned u; float f; } a;
  a.u = ((unsigned)(unsigned short)s) << 16;
  return a.f;
}
__device__ __forceinline__ short f2bf(float f) {  // RNE
  union { float f; unsigned u; } a;
  a.f = f;
  unsigned r = (a.u + 0x7fff + ((a.u >> 16) & 1)) >> 16;
  return (short)r;
}
// async 16B/lane global->LDS; lds base must be wave-uniform
__device__ __forceinline__ void dma16(const short* g, short* l) {
  __builtin_amdgcn_global_load_lds(
      (const __attribute__((address_space(1))) char*)g,
      (__attribute__((address_space(3))) char*)l, 16, 0, 0);
}

// 8 waves: wnf = wv&3 (16-oc slice per gate), whalf = wv>>2 (px half).
// LDS: As2[2][8192] gate-pair ping-pong (pre-swizzled W, linear DMA),
// Bs[3][66][64] halo (slot s = px+1; slots 0/65 zero; content swizzled
// ^(s&7)<<3 via pre-swizzled h_sw), xs[3][64].
template <bool HAS_X>
__global__ __launch_bounds__(512) void lstm_mfma_k(
    const short* __restrict__ hin,   // [32][4096][64] bf16, PRE-SWIZZLED
    const short* __restrict__ W,     // [9][256][64] bf16, pre-swizzled
    const float* __restrict__ wx,    // [256][9] f32 (x-part) or null
    const float* __restrict__ xpl,   // x + t*HW (batch stride 12*HW) or null
    const float* __restrict__ bias,  // [256] f32
    const float* __restrict__ cin,   // [32][4096][64] f32
    const short* __restrict__ zbuf,  // 1 KB zeros (border rows)
    short* __restrict__ hout,        // PRE-SWIZZLED store
    float* __restrict__ cout) {
  const int b = blockIdx.x;        // 0..31 batch (fast dim -> XCD spread)
  const int y = blockIdx.y;        // 0..63 row   (same-b rows co-XCD)
  const int tid = threadIdx.x;
  const int lane = tid & 63;
  const int wv = tid >> 6;         // 0..7
  const int wnf = wv & 3;          // oc slice within each gate
  const int whalf = wv >> 2;       // 0..1 px half
  const int col = lane & 15;
  const int quad = lane >> 4;

  __shared__ short As2[2][8192];   // 2 x 16 KB gate-pair halves
  __shared__ short Bs[3 * 66 * 64];
  __shared__ float xs[3][64];

  const short* hb = hin + (size_t)b * (HW * 64);
  // ---- DMA B halo: rows y-1..y+1; wave wv covers px 8wv..8wv+7 per row ----
#pragma unroll
  for (int r = 0; r < 3; ++r) {
    const int py = y - 1 + r;
    const short* src = (py >= 0 && py < 64)
        ? hb + ((py * 64 + 8 * wv + (lane >> 3)) * 64 + (lane & 7) * 8)
        : zbuf + lane * 8;
    dma16(src, &Bs[(r * 66 + 8 * wv + 1) * 64]);
  }
  // ---- DMA A: buf0 <- (tap0, gates 0-1) ----
  dma16(W + (wv * 64 + lane) * 8, &As2[0][wv * 64 * 8]);
  dma16(W + (512 + wv * 64 + lane) * 8, &As2[0][(512 + wv * 64) * 8]);
  // ---- zero x-border slots 0 and 65: 3 rows x 2 x 8 chunks ----
  if (tid < 48) {
    const int r = tid >> 4;
    const int s = ((tid >> 3) & 1) * 65;
    const int ch0 = (tid & 7) * 8;
    bf16x8 z = {0, 0, 0, 0, 0, 0, 0, 0};
    *reinterpret_cast<bf16x8*>(&Bs[(r * 66 + s) * 64 + ch0]) = z;
  }
  if (HAS_X) {
    if (tid < 192) {
      const float* xb = xpl + (size_t)b * (12 * HW);
      const int r = tid >> 6, cx = tid & 63;
      const int py = y - 1 + r;
      xs[r][cx] = (py >= 0 && py < 64) ? xb[py * 64 + cx] : 0.f;
    }
  }
  __syncthreads();   // drains all DMA (implicit vmcnt(0) before s_barrier)

  // issue buf1 <- (tap0, gates 2-3); lands by next barrier
  dma16(W + 8192 + (wv * 64 + lane) * 8, &As2[1][wv * 64 * 8]);
  dma16(W + 8192 + (512 + wv * 64 + lane) * 8, &As2[1][(512 + wv * 64) * 8]);

  f32x4 acc[4][2];  // [gate][local n-tile]
#pragma unroll
  for (int g = 0; g < 4; ++g) {
    const int oc0 = g * 64 + wnf * 16 + quad * 4;
#pragma unroll
    for (int nt = 0; nt < 2; ++nt)
#pragma unroll
      for (int r = 0; r < 4; ++r) acc[g][nt][r] = bias[oc0 + r];
  }

  if (HAS_X) {  // overlaps with buf1 DMA
#pragma unroll
    for (int nt = 0; nt < 2; ++nt) {
      const int px = whalf * 32 + nt * 16 + col;
#pragma unroll
      for (int tap = 0; tap < 9; ++tap) {
        const int pxx = px + (tap % 3) - 1;
        const float xv = (pxx >= 0 && pxx < 64) ? xs[tap / 3][pxx] : 0.f;
#pragma unroll
        for (int g = 0; g < 4; ++g) {
          const int oc0 = g * 64 + wnf * 16 + quad * 4;
#pragma unroll
          for (int r = 0; r < 4; ++r)
            acc[g][nt][r] = fmaf(xv, wx[(oc0 + r) * 9 + tap], acc[g][nt][r]);
        }
      }
    }
  }

  // ---- main loop: 18 phases (tap x gate-pair), A ping-pong via DMA ----
  const int axr = (col & 7) << 3;
#pragma unroll
  for (int k = 0; k < 18; ++k) {
    const int tap = k >> 1, gp = k & 1, p = k & 1;
    if (k > 0) {
      __syncthreads();   // prev-phase reads done + this buf's DMA drained
      if (k < 17) {      // DMA phase k+1 into the buffer just freed
        const int nk = k + 1;
        const short* src = W + (nk >> 1) * 16384 + (nk & 1) * 8192;
        dma16(src + (wv * 64 + lane) * 8, &As2[nk & 1][wv * 64 * 8]);
        dma16(src + (512 + wv * 64 + lane) * 8, &As2[nk & 1][(512 + wv * 64) * 8]);
      }
    }
    const int hr = tap / 3;
    const int sb = col + tap % 3;        // slot base (= px+dx+1 mod offsets)
    const int sx = (sb & 7) << 3;        // whalf*32 / nt*16 keep low 3 bits
    const int srow = (hr * 66 + whalf * 32 + sb) * 64;
#pragma unroll
    for (int kc = 0; kc < 2; ++kc) {
      const int chb = kc * 32 + quad * 8;
      const int abase = ((wnf * 16 + col) * 64 + chb) ^ axr;
      const int bbase = (srow + chb) ^ sx;
      bf16x8 a0 = *reinterpret_cast<const bf16x8*>(&As2[p][abase]);
      bf16x8 a1 = *reinterpret_cast<const bf16x8*>(&As2[p][abase + 4096]);
      bf16x8 b0 = *reinterpret_cast<const bf16x8*>(&Bs[bbase]);
      bf16x8 b1 = *reinterpret_cast<const bf16x8*>(&Bs[bbase + 1024]);
      __builtin_amdgcn_s_setprio(1);
      acc[gp * 2][0] = __builtin_amdgcn_mfma_f32_16x16x32_bf16(a0, b0, acc[gp * 2][0], 0, 0, 0);
      acc[gp * 2][1] = __builtin_amdgcn_mfma_f32_16x16x32_bf16(a0, b1, acc[gp * 2][1], 0, 0, 0);
      acc[gp * 2 + 1][0] = __builtin_amdgcn_mfma_f32_16x16x32_bf16(a1, b0, acc[gp * 2 + 1][0], 0, 0, 0);
      acc[gp * 2 + 1][1] = __builtin_amdgcn_mfma_f32_16x16x32_bf16(a1, b1, acc[gp * 2 + 1][1], 0, 0, 0);
      __builtin_amdgcn_s_setprio(0);
    }
  }

  // ---- in-register epilogue; h stored PRE-SWIZZLED ----
  const int nf0 = wnf * 16 + quad * 4;
#pragma unroll
  for (int nt = 0; nt < 2; ++nt) {
    const int px = whalf * 32 + nt * 16 + col;
    const int swz = ((px + 1) & 7) << 3;
    const size_t pix = (size_t)b * HW + y * 64 + px;
    f32x4 cold = *reinterpret_cast<const f32x4*>(cin + pix * 64 + nf0);
    f32x4 cnew;
    short hnew[4];
#pragma unroll
    for (int r = 0; r < 4; ++r) {
      float i_ = fsig(acc[0][nt][r]);
      float f_ = fsig(acc[1][nt][r]);
      float o_ = fsig(acc[2][nt][r]);
      float g_ = ftanh(acc[3][nt][r]);
      float cn = fmaf(f_, cold[r], i_ * g_);
      cnew[r] = cn;
      hnew[r] = f2bf(o_ * ftanh(cn));
    }
    *reinterpret_cast<f32x4*>(cout + pix * 64 + nf0) = cnew;
    short4 hv = make_short4(hnew[0], hnew[1], hnew[2], hnew[3]);
    *reinterpret_cast<short4*>(hout + pix * 64 + (nf0 ^ swz)) = hv;
  }
}

// head: y[b,t,pix] = b_cnn + sum_{f,tap} wc2[tap][f] * h[pix+tap][f]
// h is pre-swizzled: group f8 lives at group f8 ^ ((px+1)&7)
__global__ __launch_bounds__(256) void head_k(const short* __restrict__ h,
                                              const float* __restrict__ wc2,
                                              const float* __restrict__ bc,
                                              float* __restrict__ yout, int t) {
  const int tid = blockIdx.x * 256 + threadIdx.x;  // 131072 threads
  const int pix = tid & 4095;
  const int b = tid >> 12;
  const int x0 = pix & 63, y0 = pix >> 6;
  float acc = bc[0];
  const short* hb = h + (size_t)b * (HW * 64);
#pragma unroll
  for (int tap = 0; tap < 9; ++tap) {
    const int yy = y0 + tap / 3 - 1, xx = x0 + (tap % 3) - 1;
    if (yy < 0 || yy > 63 || xx < 0 || xx > 63) continue;
    const short* hp = hb + (yy * 64 + xx) * 64;
    const int sw8 = (xx + 1) & 7;
    const float* wp = wc2 + tap * 64;
#pragma unroll
    for (int f8 = 0; f8 < 8; ++f8) {
      bf16x8 v = *reinterpret_cast<const bf16x8*>(hp + ((f8 ^ sw8) * 8));
#pragma unroll
      for (int j = 0; j < 8; ++j) acc = fmaf(wp[f8 * 8 + j], bf2f(v[j]), acc);
    }
  }
  yout[(size_t)(b * 12 + t) * HW + pix] = acc;
}

// encoder-vector output: transpose swizzled [b][pix][ch] bf16 -> [b][ch][pix] f32
__global__ __launch_bounds__(256) void ev_out_k(const short* __restrict__ h,
                                                float* __restrict__ out) {
  __shared__ float tl[64][65];
  const int b = blockIdx.y, pg = blockIdx.x;
  const int p0 = pg * 64;
  {
    const int pixl = threadIdx.x >> 2, c0 = (threadIdx.x & 3) * 16;
    const int sw8 = (pixl + 1) & 7;   // px = pixl (p0 multiple of 64)
    const short* hp = h + ((size_t)b * HW + p0 + pixl) * 64;
#pragma unroll
    for (int gi = 0; gi < 2; ++gi) {
      const int grp = (c0 >> 3) + gi;
      bf16x8 v = *reinterpret_cast<const bf16x8*>(hp + ((grp ^ sw8) * 8));
#pragma unroll
      for (int j = 0; j < 8; ++j) tl[pixl][grp * 8 + j] = bf2f(v[j]);
    }
  }
  __syncthreads();
  {
    const int ch = threadIdx.x >> 2, q0 = (threadIdx.x & 3) * 16;
    float* op = out + ((size_t)b * 64 + ch) * (size_t)HW + p0 + q0;
#pragma unroll
    for (int i = 0; i < 16; ++i) op[i] = tl[q0 + i][ch];
  }
}

// W_enc [256][65][3][3] f32 -> Wh bf16 [9][256][64] SWIZZLED (^(oc&7)<<3)
// + wx f32 [256][9]
__global__ __launch_bounds__(256) void reo_enc_k(const float* __restrict__ src,
                                                 short* __restrict__ Wh,
                                                 float* __restrict__ wx) {
  const int idx = blockIdx.x * 256 + threadIdx.x;
  if (idx < 9 * 256 * 64) {
    const int tap = idx >> 14, oc = (idx >> 6) & 255, c = idx & 63;
    const int dst = tap * 16384 + (((oc * 64) + c) ^ ((oc & 7) << 3));
    Wh[dst] = f2bf(src[(oc * 65 + (c + 1)) * 9 + tap]);
  }
  if (idx < 256 * 9) {
    const int oc = idx / 9, tap = idx % 9;
    wx[idx] = src[(oc * 65 + 0) * 9 + tap];
  }
}

// W_dec [256][128][3][3] f32 -> Wx bf16 [9][256][64], Wsum bf16, both swizzled
__global__ __launch_bounds__(256) void reo_dec_k(const float* __restrict__ src,
                                                 short* __restrict__ Wx,
                                                 short* __restrict__ Ws) {
  const int idx = blockIdx.x * 256 + threadIdx.x;
  if (idx >= 9 * 256 * 64) return;
  const int tap = idx >> 14, oc = (idx >> 6) & 255, c = idx & 63;
  const int dst = tap * 16384 + (((oc * 64) + c) ^ ((oc & 7) << 3));
  const float a = src[(oc * 128 + c) * 9 + tap];
  const float b = src[(oc * 128 + 64 + c) * 9 + tap];
  Wx[dst] = f2bf(a);
  Ws[dst] = f2bf(a + b);
}

// W_cnn [64][9] f32 -> [9][64] f32
__global__ __launch_bounds__(256) void reo_cnn_k(const float* __restrict__ src,
                                                 float* __restrict__ wc2) {
  const int idx = blockIdx.x * 256 + threadIdx.x;
  if (idx >= 576) return;
  wc2[idx] = src[(idx % 64) * 9 + (idx / 64)];
}

extern "C" void kernel_launch(void* const* d_in, const int* in_sizes, int n_in,
                              void* d_out, int out_size, void* d_ws, size_t ws_size,
                              hipStream_t stream) {
  const float* x = (const float*)d_in[0];       // [32,12,1,64,64] f32
  const float* W_enc = (const float*)d_in[2];
  const float* b_enc = (const float*)d_in[3];
  const float* W_dec = (const float*)d_in[4];
  const float* b_dec = (const float*)d_in[5];
  const float* W_cnn = (const float*)d_in[6];
  const float* b_cnn = (const float*)d_in[7];
  float* out = (float*)d_out;
  float* out_y = out;                 // [32][12][4096]
  float* out_ev = out + 1572864;      // [32][64][4096]

  float* ws = (float*)d_ws;
  float* cA = ws;                                // 8388608 f
  float* cB = cA + 8388608;                      // 8388608 f
  short* hA = (short*)(cB + 8388608);            // 8388608 sh
  short* hB = hA + 8388608;                      // 8388608 sh
  short* WEh = hB + 8388608;                     // 147456 sh
  short* WDx = WEh + 147456;                     // 147456 sh
  short* WDs = WDx + 147456;                     // 147456 sh
  float* wx = (float*)(WDs + 147456);            // 2304 f
  float* wc2 = wx + 2304;                        // 576 f
  short* zb = (short*)(wc2 + 576);               // 512 sh zeros (~101 MB total)

  reo_enc_k<<<(147456 + 255) / 256, 256, 0, stream>>>(W_enc, WEh, wx);
  reo_dec_k<<<(147456 + 255) / 256, 256, 0, stream>>>(W_dec, WDx, WDs);
  reo_cnn_k<<<3, 256, 0, stream>>>(W_cnn, wc2);

  hipMemsetAsync(hA, 0, 8388608 * sizeof(short), stream);
  hipMemsetAsync(cA, 0, 8388608 * sizeof(float), stream);
  hipMemsetAsync(zb, 0, 512 * sizeof(short), stream);

  dim3 gridL(32, 64), blkL(512);   // x=batch (XCD-fast), y=row; 1 row/block
  dim3 gridE(64, 32), blkE(256);
  short *ha = hA, *hb = hB;
  float *ca = cA, *cb = cB;

  // ---- encoder ----
  for (int t = 0; t < 12; ++t) {
    lstm_mfma_k<true><<<gridL, blkL, 0, stream>>>(ha, WEh, wx, x + t * HW,
                                                  b_enc, ca, zb, hb, cb);
    { short* tm = ha; ha = hb; hb = tm; }
    { float* tm = ca; ca = cb; cb = tm; }
  }
  // ha = h_enc (swizzled) -> output 1 (un-swizzled transpose to [b][ch][pix])
  ev_out_k<<<gridE, blkE, 0, stream>>>(ha, out_ev);

  // fresh zero c for decoder
  hipMemsetAsync(cb, 0, 8388608 * sizeof(float), stream);
  { float* tm = ca; ca = cb; cb = tm; }  // ca = zeroed c

  // ---- decoder ----
  for (int t = 0; t < 12; ++t) {
    lstm_mfma_k<false><<<gridL, blkL, 0, stream>>>(
        ha, (t == 0) ? WDx : WDs, nullptr, nullptr, b_dec, ca, zb, hb, cb);
    { short* tm = ha; ha = hb; hb = tm; }
    { float* tm = ca; ca = cb; cb = tm; }
    head_k<<<512, 256, 0, stream>>>(ha, wc2, b_cnn, out_y, t);
  }
}

// Round 8
// 1939.564 us; speedup vs baseline: 2.2284x; 1.0020x over previous
//
#include <hip/hip_runtime.h>
#include <hip/hip_bf16.h>

// EncoderDecoderConvLSTM — Round 18: counted-vmcnt DMA pipeline (T4).
// R12/R15/R17 all plateau 96-110 us: every variant drains vmcnt(0) at each
// phase barrier (__syncthreads), so the ~200-500cy L2 latency of the next
// A-block DMA is exposed 17x per block with no co-resident block to fill it
// (2 waves/SIMD bin: 108 VGPR + 32 AGPR = 140 > 128). Fix per T3/T4: A in a
// 3-buffer rotation (48 KB), DMA issued 2 PHASES ahead, each phase waits
// s_waitcnt vmcnt(2) (own loads only - can only over-wait) + RAW s_barrier;
// vmcnt reaches 0 only at the last phase. Buffer (k+2)%3's previous reader
// is phase k-1, fenced by barrier k -> no race. Everything else = R17:
// B halo DMA'd from pre-swizzled h, zero-page border redirect, fused epilogue.
// h_sw [b][4096][64] bf16; c f32; W [9][256][64] bf16 pre-swizzled (^(oc&7)<<3).

#define HW 4096
#define NF 64

typedef __attribute__((ext_vector_type(8))) short bf16x8;
typedef __attribute__((ext_vector_type(4))) float f32x4;

__device__ __forceinline__ float fsig(float v) {
  return __builtin_amdgcn_rcpf(1.f + __expf(-v));
}
__device__ __forceinline__ float ftanh(float v) {
  float vc = fminf(fmaxf(v, -15.f), 15.f);
  float e = __expf(2.f * vc);
  return (e - 1.f) * __builtin_amdgcn_rcpf(e + 1.f);
}
__device__ __forceinline__ float bf2f(short s) {
  union { unsigned u; float f; } a;
  a.u = ((unsigned)(unsigned short)s) << 16;
  return a.f;
}
__device__ __forceinline__ short f2bf(float f) {  // RNE
  union { float f; unsigned u; } a;
  a.f = f;
  unsigned r = (a.u + 0x7fff + ((a.u >> 16) & 1)) >> 16;
  return (short)r;
}
// async 16B/lane global->LDS; lds base must be wave-uniform
__device__ __forceinline__ void dma16(const short* g, short* l) {
  __builtin_amdgcn_global_load_lds(
      (const __attribute__((address_space(1))) char*)g,
      (__attribute__((address_space(3))) char*)l, 16, 0, 0);
}

// 8 waves: wnf = wv&3 (16-oc slice per gate), whalf = wv>>2 (px half).
// LDS: As3[3][8192] rotating gate-pair buffers (pre-swizzled W, linear DMA),
// Bs[3][66][64] halo (slot s = px+1; slots 0/65 zero; content swizzled
// ^(s&7)<<3 via pre-swizzled h_sw), xs[3][64].
template <bool HAS_X>
__global__ __launch_bounds__(512) void lstm_mfma_k(
    const short* __restrict__ hin,   // [32][4096][64] bf16, PRE-SWIZZLED
    const short* __restrict__ W,     // [9][256][64] bf16, pre-swizzled
    const float* __restrict__ wx,    // [256][9] f32 (x-part) or null
    const float* __restrict__ xpl,   // x + t*HW (batch stride 12*HW) or null
    const float* __restrict__ bias,  // [256] f32
    const float* __restrict__ cin,   // [32][4096][64] f32
    const short* __restrict__ zbuf,  // 1 KB zeros (border rows)
    short* __restrict__ hout,        // PRE-SWIZZLED store
    float* __restrict__ cout) {
  const int b = blockIdx.x;        // 0..31 batch (fast dim -> XCD spread)
  const int y = blockIdx.y;        // 0..63 row   (same-b rows co-XCD)
  const int tid = threadIdx.x;
  const int lane = tid & 63;
  const int wv = tid >> 6;         // 0..7
  const int wnf = wv & 3;          // oc slice within each gate
  const int whalf = wv >> 2;       // 0..1 px half
  const int col = lane & 15;
  const int quad = lane >> 4;

  __shared__ short As3[3][8192];   // 3 x 16 KB gate-pair buffers
  __shared__ short Bs[3 * 66 * 64];
  __shared__ float xs[3][64];

  const short* hb = hin + (size_t)b * (HW * 64);
  // ---- DMA B halo: rows y-1..y+1; wave wv covers px 8wv..8wv+7 per row ----
#pragma unroll
  for (int r = 0; r < 3; ++r) {
    const int py = y - 1 + r;
    const short* src = (py >= 0 && py < 64)
        ? hb + ((py * 64 + 8 * wv + (lane >> 3)) * 64 + (lane & 7) * 8)
        : zbuf + lane * 8;
    dma16(src, &Bs[(r * 66 + 8 * wv + 1) * 64]);
  }
  // ---- DMA A: loads(0) -> buf0, loads(1) -> buf1 (phase k = tap k>>1,
  // gate-pair k&1 at W + (k>>1)*16384 + (k&1)*8192) ----
#pragma unroll
  for (int k = 0; k < 2; ++k) {
    const short* src = W + (k >> 1) * 16384 + (k & 1) * 8192;
    dma16(src + (wv * 64 + lane) * 8, &As3[k][wv * 64 * 8]);
    dma16(src + (512 + wv * 64 + lane) * 8, &As3[k][(512 + wv * 64) * 8]);
  }
  // ---- zero x-border slots 0 and 65: 3 rows x 2 x 8 chunks ----
  if (tid < 48) {
    const int r = tid >> 4;
    const int s = ((tid >> 3) & 1) * 65;
    const int ch0 = (tid & 7) * 8;
    bf16x8 z = {0, 0, 0, 0, 0, 0, 0, 0};
    *reinterpret_cast<bf16x8*>(&Bs[(r * 66 + s) * 64 + ch0]) = z;
  }
  if (HAS_X) {
    if (tid < 192) {
      const float* xb = xpl + (size_t)b * (12 * HW);
      const int r = tid >> 6, cx = tid & 63;
      const int py = y - 1 + r;
      xs[r][cx] = (py >= 0 && py < 64) ? xb[py * 64 + cx] : 0.f;
    }
  }
  // B halo + loads(0) complete; loads(1) (2 newest) may stay in flight.
  asm volatile("s_waitcnt vmcnt(2) lgkmcnt(0)" ::: "memory");
  __builtin_amdgcn_s_barrier();

  f32x4 acc[4][2];  // [gate][local n-tile]
#pragma unroll
  for (int g = 0; g < 4; ++g) {
    const int oc0 = g * 64 + wnf * 16 + quad * 4;
#pragma unroll
    for (int nt = 0; nt < 2; ++nt)
#pragma unroll
      for (int r = 0; r < 4; ++r) acc[g][nt][r] = bias[oc0 + r];
  }

  if (HAS_X) {  // overlaps with in-flight loads(1)
#pragma unroll
    for (int nt = 0; nt < 2; ++nt) {
      const int px = whalf * 32 + nt * 16 + col;
#pragma unroll
      for (int tap = 0; tap < 9; ++tap) {
        const int pxx = px + (tap % 3) - 1;
        const float xv = (pxx >= 0 && pxx < 64) ? xs[tap / 3][pxx] : 0.f;
#pragma unroll
        for (int g = 0; g < 4; ++g) {
          const int oc0 = g * 64 + wnf * 16 + quad * 4;
#pragma unroll
          for (int r = 0; r < 4; ++r)
            acc[g][nt][r] = fmaf(xv, wx[(oc0 + r) * 9 + tap], acc[g][nt][r]);
        }
      }
    }
  }

  // ---- main loop: 18 phases (tap x gate-pair); A rotates over 3 buffers;
  // loads(k+2) issued at phase k; wait is COUNTED (vmcnt(2)), drain only at
  // the final phase. Raw s_barrier (no implicit vmcnt(0) drain). ----
  const int axr = (col & 7) << 3;
#pragma unroll
  for (int k = 0; k < 18; ++k) {
    const int tap = k >> 1, gp = k & 1, p = k % 3;
    if (k > 0) {
      if (k == 17)
        asm volatile("s_waitcnt vmcnt(0)" ::: "memory");
      else
        asm volatile("s_waitcnt vmcnt(2)" ::: "memory");
      __builtin_amdgcn_s_barrier();
    }
    if (k + 2 < 18) {  // DMA phase k+2 into buffer freed by phase k-1
      const int nk = k + 2;
      const short* src = W + (nk >> 1) * 16384 + (nk & 1) * 8192;
      dma16(src + (wv * 64 + lane) * 8, &As3[nk % 3][wv * 64 * 8]);
      dma16(src + (512 + wv * 64 + lane) * 8, &As3[nk % 3][(512 + wv * 64) * 8]);
    }
    const int hr = tap / 3;
    const int sb = col + tap % 3;        // slot base (= px+dx+1 mod offsets)
    const int sx = (sb & 7) << 3;        // whalf*32 / nt*16 keep low 3 bits
    const int srow = (hr * 66 + whalf * 32 + sb) * 64;
#pragma unroll
    for (int kc = 0; kc < 2; ++kc) {
      const int chb = kc * 32 + quad * 8;
      const int abase = ((wnf * 16 + col) * 64 + chb) ^ axr;
      const int bbase = (srow + chb) ^ sx;
      bf16x8 a0 = *reinterpret_cast<const bf16x8*>(&As3[p][abase]);
      bf16x8 a1 = *reinterpret_cast<const bf16x8*>(&As3[p][abase + 4096]);
      bf16x8 b0 = *reinterpret_cast<const bf16x8*>(&Bs[bbase]);
      bf16x8 b1 = *reinterpret_cast<const bf16x8*>(&Bs[bbase + 1024]);
      __builtin_amdgcn_s_setprio(1);
      acc[gp * 2][0] = __builtin_amdgcn_mfma_f32_16x16x32_bf16(a0, b0, acc[gp * 2][0], 0, 0, 0);
      acc[gp * 2][1] = __builtin_amdgcn_mfma_f32_16x16x32_bf16(a0, b1, acc[gp * 2][1], 0, 0, 0);
      acc[gp * 2 + 1][0] = __builtin_amdgcn_mfma_f32_16x16x32_bf16(a1, b0, acc[gp * 2 + 1][0], 0, 0, 0);
      acc[gp * 2 + 1][1] = __builtin_amdgcn_mfma_f32_16x16x32_bf16(a1, b1, acc[gp * 2 + 1][1], 0, 0, 0);
      __builtin_amdgcn_s_setprio(0);
    }
  }

  // ---- in-register epilogue; h stored PRE-SWIZZLED ----
  const int nf0 = wnf * 16 + quad * 4;
#pragma unroll
  for (int nt = 0; nt < 2; ++nt) {
    const int px = whalf * 32 + nt * 16 + col;
    const int swz = ((px + 1) & 7) << 3;
    const size_t pix = (size_t)b * HW + y * 64 + px;
    f32x4 cold = *reinterpret_cast<const f32x4*>(cin + pix * 64 + nf0);
    f32x4 cnew;
    short hnew[4];
#pragma unroll
    for (int r = 0; r < 4; ++r) {
      float i_ = fsig(acc[0][nt][r]);
      float f_ = fsig(acc[1][nt][r]);
      float o_ = fsig(acc[2][nt][r]);
      float g_ = ftanh(acc[3][nt][r]);
      float cn = fmaf(f_, cold[r], i_ * g_);
      cnew[r] = cn;
      hnew[r] = f2bf(o_ * ftanh(cn));
    }
    *reinterpret_cast<f32x4*>(cout + pix * 64 + nf0) = cnew;
    short4 hv = make_short4(hnew[0], hnew[1], hnew[2], hnew[3]);
    *reinterpret_cast<short4*>(hout + pix * 64 + (nf0 ^ swz)) = hv;
  }
}

// head: y[b,t,pix] = b_cnn + sum_{f,tap} wc2[tap][f] * h[pix+tap][f]
// h is pre-swizzled: group f8 lives at group f8 ^ ((px+1)&7)
__global__ __launch_bounds__(256) void head_k(const short* __restrict__ h,
                                              const float* __restrict__ wc2,
                                              const float* __restrict__ bc,
                                              float* __restrict__ yout, int t) {
  const int tid = blockIdx.x * 256 + threadIdx.x;  // 131072 threads
  const int pix = tid & 4095;
  const int b = tid >> 12;
  const int x0 = pix & 63, y0 = pix >> 6;
  float acc = bc[0];
  const short* hb = h + (size_t)b * (HW * 64);
#pragma unroll
  for (int tap = 0; tap < 9; ++tap) {
    const int yy = y0 + tap / 3 - 1, xx = x0 + (tap % 3) - 1;
    if (yy < 0 || yy > 63 || xx < 0 || xx > 63) continue;
    const short* hp = hb + (yy * 64 + xx) * 64;
    const int sw8 = (xx + 1) & 7;
    const float* wp = wc2 + tap * 64;
#pragma unroll
    for (int f8 = 0; f8 < 8; ++f8) {
      bf16x8 v = *reinterpret_cast<const bf16x8*>(hp + ((f8 ^ sw8) * 8));
#pragma unroll
      for (int j = 0; j < 8; ++j) acc = fmaf(wp[f8 * 8 + j], bf2f(v[j]), acc);
    }
  }
  yout[(size_t)(b * 12 + t) * HW + pix] = acc;
}

// encoder-vector output: transpose swizzled [b][pix][ch] bf16 -> [b][ch][pix] f32
__global__ __launch_bounds__(256) void ev_out_k(const short* __restrict__ h,
                                                float* __restrict__ out) {
  __shared__ float tl[64][65];
  const int b = blockIdx.y, pg = blockIdx.x;
  const int p0 = pg * 64;
  {
    const int pixl = threadIdx.x >> 2, c0 = (threadIdx.x & 3) * 16;
    const int sw8 = (pixl + 1) & 7;   // px = pixl (p0 multiple of 64)
    const short* hp = h + ((size_t)b * HW + p0 + pixl) * 64;
#pragma unroll
    for (int gi = 0; gi < 2; ++gi) {
      const int grp = (c0 >> 3) + gi;
      bf16x8 v = *reinterpret_cast<const bf16x8*>(hp + ((grp ^ sw8) * 8));
#pragma unroll
      for (int j = 0; j < 8; ++j) tl[pixl][grp * 8 + j] = bf2f(v[j]);
    }
  }
  __syncthreads();
  {
    const int ch = threadIdx.x >> 2, q0 = (threadIdx.x & 3) * 16;
    float* op = out + ((size_t)b * 64 + ch) * (size_t)HW + p0 + q0;
#pragma unroll
    for (int i = 0; i < 16; ++i) op[i] = tl[q0 + i][ch];
  }
}

// W_enc [256][65][3][3] f32 -> Wh bf16 [9][256][64] SWIZZLED (^(oc&7)<<3)
// + wx f32 [256][9]
__global__ __launch_bounds__(256) void reo_enc_k(const float* __restrict__ src,
                                                 short* __restrict__ Wh,
                                                 float* __restrict__ wx) {
  const int idx = blockIdx.x * 256 + threadIdx.x;
  if (idx < 9 * 256 * 64) {
    const int tap = idx >> 14, oc = (idx >> 6) & 255, c = idx & 63;
    const int dst = tap * 16384 + (((oc * 64) + c) ^ ((oc & 7) << 3));
    Wh[dst] = f2bf(src[(oc * 65 + (c + 1)) * 9 + tap]);
  }
  if (idx < 256 * 9) {
    const int oc = idx / 9, tap = idx % 9;
    wx[idx] = src[(oc * 65 + 0) * 9 + tap];
  }
}

// W_dec [256][128][3][3] f32 -> Wx bf16 [9][256][64], Wsum bf16, both swizzled
__global__ __launch_bounds__(256) void reo_dec_k(const float* __restrict__ src,
                                                 short* __restrict__ Wx,
                                                 short* __restrict__ Ws) {
  const int idx = blockIdx.x * 256 + threadIdx.x;
  if (idx >= 9 * 256 * 64) return;
  const int tap = idx >> 14, oc = (idx >> 6) & 255, c = idx & 63;
  const int dst = tap * 16384 + (((oc * 64) + c) ^ ((oc & 7) << 3));
  const float a = src[(oc * 128 + c) * 9 + tap];
  const float b = src[(oc * 128 + 64 + c) * 9 + tap];
  Wx[dst] = f2bf(a);
  Ws[dst] = f2bf(a + b);
}

// W_cnn [64][9] f32 -> [9][64] f32
__global__ __launch_bounds__(256) void reo_cnn_k(const float* __restrict__ src,
                                                 float* __restrict__ wc2) {
  const int idx = blockIdx.x * 256 + threadIdx.x;
  if (idx >= 576) return;
  wc2[idx] = src[(idx % 64) * 9 + (idx / 64)];
}

extern "C" void kernel_launch(void* const* d_in, const int* in_sizes, int n_in,
                              void* d_out, int out_size, void* d_ws, size_t ws_size,
                              hipStream_t stream) {
  const float* x = (const float*)d_in[0];       // [32,12,1,64,64] f32
  const float* W_enc = (const float*)d_in[2];
  const float* b_enc = (const float*)d_in[3];
  const float* W_dec = (const float*)d_in[4];
  const float* b_dec = (const float*)d_in[5];
  const float* W_cnn = (const float*)d_in[6];
  const float* b_cnn = (const float*)d_in[7];
  float* out = (float*)d_out;
  float* out_y = out;                 // [32][12][4096]
  float* out_ev = out + 1572864;      // [32][64][4096]

  float* ws = (float*)d_ws;
  float* cA = ws;                                // 8388608 f
  float* cB = cA + 8388608;                      // 8388608 f
  short* hA = (short*)(cB + 8388608);            // 8388608 sh
  short* hB = hA + 8388608;                      // 8388608 sh
  short* WEh = hB + 8388608;                     // 147456 sh
  short* WDx = WEh + 147456;                     // 147456 sh
  short* WDs = WDx + 147456;                     // 147456 sh
  float* wx = (float*)(WDs + 147456);            // 2304 f
  float* wc2 = wx + 2304;                        // 576 f
  short* zb = (short*)(wc2 + 576);               // 512 sh zeros (~101 MB total)

  reo_enc_k<<<(147456 + 255) / 256, 256, 0, stream>>>(W_enc, WEh, wx);
  reo_dec_k<<<(147456 + 255) / 256, 256, 0, stream>>>(W_dec, WDx, WDs);
  reo_cnn_k<<<3, 256, 0, stream>>>(W_cnn, wc2);

  hipMemsetAsync(hA, 0, 8388608 * sizeof(short), stream);
  hipMemsetAsync(cA, 0, 8388608 * sizeof(float), stream);
  hipMemsetAsync(zb, 0, 512 * sizeof(short), stream);

  dim3 gridL(32, 64), blkL(512);   // x=batch (XCD-fast), y=row; 1 row/block
  dim3 gridE(64, 32), blkE(256);
  short *ha = hA, *hb = hB;
  float *ca = cA, *cb = cB;

  // ---- encoder ----
  for (int t = 0; t < 12; ++t) {
    lstm_mfma_k<true><<<gridL, blkL, 0, stream>>>(ha, WEh, wx, x + t * HW,
                                                  b_enc, ca, zb, hb, cb);
    { short* tm = ha; ha = hb; hb = tm; }
    { float* tm = ca; ca = cb; cb = tm; }
  }
  // ha = h_enc (swizzled) -> output 1 (un-swizzled transpose to [b][ch][pix])
  ev_out_k<<<gridE, blkE, 0, stream>>>(ha, out_ev);

  // fresh zero c for decoder
  hipMemsetAsync(cb, 0, 8388608 * sizeof(float), stream);
  { float* tm = ca; ca = cb; cb = tm; }  // ca = zeroed c

  // ---- decoder ----
  for (int t = 0; t < 12; ++t) {
    lstm_mfma_k<false><<<gridL, blkL, 0, stream>>>(
        ha, (t == 0) ? WDx : WDs, nullptr, nullptr, b_dec, ca, zb, hb, cb);
    { short* tm = ha; ha = hb; hb = tm; }
    { float* tm = ca; ca = cb; cb = tm; }
    head_k<<<512, 256, 0, stream>>>(ha, wc2, b_cnn, out_y, t);
  }
}